// Round 1
// baseline (3684.422 us; speedup 1.0000x reference)
//
#include <hip/hip_runtime.h>
#include <math.h>

#define MULC   32
#define DIMC   128
#define WNUM   4096
#define EPSV   1e-5f
#define IS3    0.57735026918962576f   // 1/sqrt(3)
#define PNRM   0.125f                 // 1/sqrt(2*32)

// ---------------- K1: h = relu(edge_attr @ W1 + b1) ----------------
// 256 threads, 16 edges per WG. W1 (128x128 f32 = 64KB) staged in LDS.
__global__ __launch_bounds__(256) void k1_fc(const float* __restrict__ ea,
                                             const float* __restrict__ W1,
                                             const float* __restrict__ b1,
                                             float* __restrict__ h, int E) {
    __shared__ float W1s[128 * 128];
    const int tid = threadIdx.x;
    for (int idx = tid; idx < 4096; idx += 256) {
        int k = idx >> 5, j4 = (idx & 31) * 4;
        *reinterpret_cast<float4*>(&W1s[k * 128 + j4]) =
            *reinterpret_cast<const float4*>(W1 + (size_t)k * 128 + j4);
    }
    __syncthreads();
    const int e  = blockIdx.x * 16 + (tid >> 4);
    const int j0 = (tid & 15) * 8;
    if (e >= E) return;
    float acc[8];
#pragma unroll
    for (int j = 0; j < 8; ++j) acc[j] = b1[j0 + j];
    const float* ear = ea + (size_t)e * 128;
    for (int k = 0; k < 128; ++k) {
        float a = ear[k];
        float4 wv0 = *reinterpret_cast<float4*>(&W1s[k * 128 + j0]);
        float4 wv1 = *reinterpret_cast<float4*>(&W1s[k * 128 + j0 + 4]);
        acc[0] += a * wv0.x; acc[1] += a * wv0.y; acc[2] += a * wv0.z; acc[3] += a * wv0.w;
        acc[4] += a * wv1.x; acc[5] += a * wv1.y; acc[6] += a * wv1.z; acc[7] += a * wv1.w;
    }
    float* hr = h + (size_t)e * 128 + j0;
#pragma unroll
    for (int j = 0; j < 8; ++j) hr[j] = acc[j] > 0.f ? acc[j] : 0.f;
}

// ---------------- K2: fused GEMM2 + tensor product ----------------
// 64 threads (1 wave), 32 edges per WG. Loops over 128 chunks (block b, u),
// each chunk = 32 W2 columns staged in LDS; contracts immediately.
#define HT_STRIDE 36   // hsT row stride (floats): 16B-aligned, conflict-free
#define XS_STRIDE 129

__global__ __launch_bounds__(64) void k2_tp(const float* __restrict__ h,
                                            const float* __restrict__ na,
                                            const int* __restrict__ ei,
                                            const float* __restrict__ sh,
                                            const float* __restrict__ W2,
                                            const float* __restrict__ b2,
                                            float* __restrict__ tp, int E) {
    __shared__ float hsT[128 * HT_STRIDE];   // [k][e_local]
    __shared__ float xs[32 * XS_STRIDE];     // [e_local][k] (node_attr gathered)
    __shared__ float w2s[128 * 32];          // chunk [k][w']
    __shared__ float shs[32 * 4];

    const int tid = threadIdx.x;
    const int e0  = blockIdx.x * 32;
    const int* dst = ei + E;

    // stage h (transposed) and gathered node_attr
    for (int idx = tid; idx < 1024; idx += 64) {
        int el = idx >> 5, k4 = (idx & 31) * 4;
        int e = e0 + el;
        float4 hv = make_float4(0.f, 0.f, 0.f, 0.f), xv = hv;
        if (e < E) {
            hv = *reinterpret_cast<const float4*>(h + (size_t)e * 128 + k4);
            int d = dst[e];
            xv = *reinterpret_cast<const float4*>(na + (size_t)d * 128 + k4);
        }
        hsT[(k4 + 0) * HT_STRIDE + el] = hv.x;
        hsT[(k4 + 1) * HT_STRIDE + el] = hv.y;
        hsT[(k4 + 2) * HT_STRIDE + el] = hv.z;
        hsT[(k4 + 3) * HT_STRIDE + el] = hv.w;
        float* xp = &xs[el * XS_STRIDE + k4];
        xp[0] = xv.x; xp[1] = xv.y; xp[2] = xv.z; xp[3] = xv.w;
    }
    for (int idx = tid; idx < 128; idx += 64) {
        int el = idx >> 2, c = idx & 3;
        int e = e0 + el;
        shs[el * 4 + c] = (e < E) ? sh[(size_t)e * 4 + c] : 0.f;
    }
    __syncthreads();

    const int eg = tid >> 3;        // 0..7 -> edges eg*4..eg*4+3
    const int wg = tid & 7;         // 0..7 -> w' wg*4..wg*4+3
    const int w0 = wg * 4;

    float sh0v[4], sh1v[4][3];
#pragma unroll
    for (int i = 0; i < 4; ++i) {
        int el = eg * 4 + i;
        sh0v[i]    = shs[el * 4 + 0];
        sh1v[i][0] = shs[el * 4 + 1];
        sh1v[i][1] = shs[el * 4 + 2];
        sh1v[i][2] = shs[el * 4 + 3];
    }

    float acc0[4][4] = {};      // out0 accumulator (A + IS3*D parts)
    float accB[4][4] = {};      // y_B
    float accC[4][4][3] = {};   // y_C per i-component

    for (int c = 0; c < 128; ++c) {
        const int b = c >> 5, u = c & 31;
        const int colbase = b * 1024 + u * 32;
        __syncthreads();
        for (int idx = tid; idx < 1024; idx += 64) {
            int k = idx >> 3, j4 = (idx & 7) * 4;
            *reinterpret_cast<float4*>(&w2s[k * 32 + j4]) =
                *reinterpret_cast<const float4*>(W2 + (size_t)k * 4096 + colbase + j4);
        }
        __syncthreads();

        float dot[4][4] = {};
        for (int k = 0; k < 128; ++k) {
            float4 wv = *reinterpret_cast<float4*>(&w2s[k * 32 + w0]);
            float4 hv = *reinterpret_cast<float4*>(&hsT[k * HT_STRIDE + eg * 4]);
            dot[0][0] += hv.x * wv.x; dot[0][1] += hv.x * wv.y; dot[0][2] += hv.x * wv.z; dot[0][3] += hv.x * wv.w;
            dot[1][0] += hv.y * wv.x; dot[1][1] += hv.y * wv.y; dot[1][2] += hv.y * wv.z; dot[1][3] += hv.y * wv.w;
            dot[2][0] += hv.z * wv.x; dot[2][1] += hv.z * wv.y; dot[2][2] += hv.z * wv.z; dot[2][3] += hv.z * wv.w;
            dot[3][0] += hv.w * wv.x; dot[3][1] += hv.w * wv.y; dot[3][2] += hv.w * wv.z; dot[3][3] += hv.w * wv.w;
        }
        float b2v[4];
#pragma unroll
        for (int j = 0; j < 4; ++j) b2v[j] = b2[colbase + w0 + j];

#pragma unroll
        for (int i = 0; i < 4; ++i) {
            const int el = eg * 4 + i;
            if (b == 0) {
                float coef = xs[el * XS_STRIDE + u] * sh0v[i];
#pragma unroll
                for (int j = 0; j < 4; ++j) acc0[i][j] += coef * (dot[i][j] + b2v[j]);
            } else if (b == 1) {
                float coef = xs[el * XS_STRIDE + u];
#pragma unroll
                for (int j = 0; j < 4; ++j) accB[i][j] += coef * (dot[i][j] + b2v[j]);
            } else if (b == 2) {
                float x10 = xs[el * XS_STRIDE + 32 + u * 3 + 0];
                float x11 = xs[el * XS_STRIDE + 32 + u * 3 + 1];
                float x12 = xs[el * XS_STRIDE + 32 + u * 3 + 2];
#pragma unroll
                for (int j = 0; j < 4; ++j) {
                    float val = dot[i][j] + b2v[j];
                    accC[i][j][0] += x10 * val;
                    accC[i][j][1] += x11 * val;
                    accC[i][j][2] += x12 * val;
                }
            } else {
                float x10 = xs[el * XS_STRIDE + 32 + u * 3 + 0];
                float x11 = xs[el * XS_STRIDE + 32 + u * 3 + 1];
                float x12 = xs[el * XS_STRIDE + 32 + u * 3 + 2];
                float dcoef = x10 * sh1v[i][0] + x11 * sh1v[i][1] + x12 * sh1v[i][2];
                dcoef *= IS3;
#pragma unroll
                for (int j = 0; j < 4; ++j) acc0[i][j] += dcoef * (dot[i][j] + b2v[j]);
            }
        }
    }

    // epilogue: tp[e][0:32]=out0, tp[e][32+w*3+t]=out1
#pragma unroll
    for (int i = 0; i < 4; ++i) {
        int e = e0 + eg * 4 + i;
        if (e >= E) continue;
        float* tpe = tp + (size_t)e * 128;
#pragma unroll
        for (int j = 0; j < 4; ++j) {
            int w = w0 + j;
            tpe[w] = PNRM * acc0[i][j];
#pragma unroll
            for (int t = 0; t < 3; ++t)
                tpe[32 + w * 3 + t] =
                    PNRM * IS3 * (sh1v[i][t] * accB[i][j] + sh0v[i] * accC[i][j][t]);
        }
    }
}

// ---------------- K3: scatter-sum over edge_src ----------------
__global__ __launch_bounds__(256) void k3_scatter(const float* __restrict__ tp,
                                                  const int* __restrict__ ei,
                                                  float* __restrict__ summed,
                                                  float* __restrict__ counts, int E) {
    size_t idx = (size_t)blockIdx.x * 256 + threadIdx.x;
    if (idx >= (size_t)E * 128) return;
    int e = (int)(idx >> 7), o = (int)(idx & 127);
    int s = ei[e];
    atomicAdd(&summed[(size_t)s * 128 + o], tp[idx]);
    if (o == 0) atomicAdd(&counts[s], 1.0f);
}

// ---------------- K4: mean + residual, BN stats ----------------
__global__ __launch_bounds__(256) void k4_pre(float* __restrict__ pre,
                                              const float* __restrict__ counts,
                                              const float* __restrict__ na,
                                              float* __restrict__ stats, int N) {
    __shared__ float bns[96];
    const int tid = threadIdx.x;
    if (tid < 96) bns[tid] = 0.f;
    __syncthreads();
    size_t idx = (size_t)blockIdx.x * 256 + tid;
    if (idx < (size_t)N * 128) {
        int n = (int)(idx >> 7), o = (int)(idx & 127);
        float c = counts[n];
        c = c > 1.f ? c : 1.f;
        float v = pre[idx] / c + na[idx];
        pre[idx] = v;
        if (o < 32) {
            atomicAdd(&bns[o], v);
            atomicAdd(&bns[32 + o], v * v);
        } else {
            atomicAdd(&bns[64 + (o - 32) / 3], v * v);
        }
    }
    __syncthreads();
    if (tid < 96) atomicAdd(&stats[tid], bns[tid]);
}

// ---------------- K5: apply batch norm ----------------
__global__ __launch_bounds__(256) void k5_bn(const float* __restrict__ pre,
                                             const float* __restrict__ stats,
                                             const float* __restrict__ bnw,
                                             const float* __restrict__ bnb,
                                             float* __restrict__ out, int N) {
    size_t idx = (size_t)blockIdx.x * 256 + threadIdx.x;
    if (idx >= (size_t)N * 128) return;
    int o = (int)(idx & 127);
    float v = pre[idx];
    float invN = 1.f / (float)N;
    if (o < 32) {
        float m   = stats[o] * invN;
        float var = stats[32 + o] * invN - m * m;
        out[idx] = (v - m) * rsqrtf(var + EPSV) * bnw[o] + bnb[o];
    } else {
        int j = (o - 32) / 3;
        float vn = rsqrtf(stats[64 + j] * invN * (1.f / 3.f) + EPSV);
        out[idx] = v * vn * bnw[32 + j];
    }
}

extern "C" void kernel_launch(void* const* d_in, const int* in_sizes, int n_in,
                              void* d_out, int out_size, void* d_ws, size_t ws_size,
                              hipStream_t stream) {
    const float* node_attr = (const float*)d_in[0];
    const int*   edge_index = (const int*)d_in[1];
    const float* edge_attr = (const float*)d_in[2];
    const float* edge_sh   = (const float*)d_in[3];
    const float* W1  = (const float*)d_in[4];
    const float* b1  = (const float*)d_in[5];
    const float* W2  = (const float*)d_in[6];
    const float* b2  = (const float*)d_in[7];
    const float* bnw = (const float*)d_in[8];
    const float* bnb = (const float*)d_in[9];

    const int N = in_sizes[0] / 128;
    const int E = in_sizes[1] / 2;

    float* ws     = (float*)d_ws;
    float* h      = ws;                         // E*128
    float* tp     = h + (size_t)E * 128;        // E*128
    float* summed = tp + (size_t)E * 128;       // N*128
    float* counts = summed + (size_t)N * 128;   // N
    float* stats  = counts + N;                 // 96

    size_t zbytes = ((size_t)N * 128 + (size_t)N + 96) * sizeof(float);
    hipMemsetAsync(summed, 0, zbytes, stream);

    k1_fc<<<(E + 15) / 16, 256, 0, stream>>>(edge_attr, W1, b1, h, E);
    k2_tp<<<(E + 31) / 32, 64, 0, stream>>>(h, node_attr, edge_index, edge_sh,
                                            W2, b2, tp, E);
    size_t etot = (size_t)E * 128;
    k3_scatter<<<(int)((etot + 255) / 256), 256, 0, stream>>>(tp, edge_index,
                                                              summed, counts, E);
    size_t ntot = (size_t)N * 128;
    k4_pre<<<(int)((ntot + 255) / 256), 256, 0, stream>>>(summed, counts,
                                                          node_attr, stats, N);
    k5_bn<<<(int)((ntot + 255) / 256), 256, 0, stream>>>(summed, stats, bnw, bnb,
                                                         (float*)d_out, N);
}

// Round 2
// 1991.301 us; speedup vs baseline: 1.8503x; 1.8503x over previous
//
#include <hip/hip_runtime.h>
#include <math.h>

#define EPSV   1e-5f
#define IS3    0.57735026918962576f   // 1/sqrt(3)
#define PNRM   0.125f                 // 1/sqrt(2*32)

typedef __attribute__((ext_vector_type(8))) short short8;
typedef __attribute__((ext_vector_type(4))) float floatx4;

static __device__ inline unsigned short f2bf(float f) {
    unsigned int u = __float_as_uint(f);
    unsigned int r = (u + 0x7fff + ((u >> 16) & 1)) >> 16;  // RNE
    return (unsigned short)r;
}

// ---------------- K0: W2 (128x4096 f32) -> W2T (4096x128 bf16) ----------------
__global__ __launch_bounds__(256) void k0_w2t(const float* __restrict__ W2,
                                              unsigned short* __restrict__ W2T) {
    __shared__ float t[32][33];
    const int c0 = blockIdx.x * 32, k0 = blockIdx.y * 32;
    const int tx = threadIdx.x & 31, ty = threadIdx.x >> 5;  // ty 0..7
#pragma unroll
    for (int i = 0; i < 4; ++i) {
        int k = ty + i * 8;
        t[k][tx] = W2[(size_t)(k0 + k) * 4096 + c0 + tx];
    }
    __syncthreads();
#pragma unroll
    for (int i = 0; i < 4; ++i) {
        int c = ty + i * 8;
        W2T[(size_t)(c0 + c) * 128 + k0 + tx] = f2bf(t[tx][c]);
    }
}

// ---------------- K1: h = relu(edge_attr @ W1 + b1) -> bf16; + counts ----------
__global__ __launch_bounds__(256) void k1_fc(const float* __restrict__ ea,
                                             const float* __restrict__ W1,
                                             const float* __restrict__ b1,
                                             const int* __restrict__ ei,
                                             unsigned short* __restrict__ h,
                                             float* __restrict__ counts, int E) {
    __shared__ float W1s[128 * 128];
    const int tid = threadIdx.x;
    for (int idx = tid; idx < 4096; idx += 256) {
        int k = idx >> 5, j4 = (idx & 31) * 4;
        *reinterpret_cast<float4*>(&W1s[k * 128 + j4]) =
            *reinterpret_cast<const float4*>(W1 + (size_t)k * 128 + j4);
    }
    __syncthreads();
    const int e  = blockIdx.x * 16 + (tid >> 4);
    const int j0 = (tid & 15) * 8;
    if (e >= E) return;
    if ((tid & 15) == 0) atomicAdd(&counts[ei[e]], 1.0f);
    float acc[8];
#pragma unroll
    for (int j = 0; j < 8; ++j) acc[j] = b1[j0 + j];
    const float* ear = ea + (size_t)e * 128;
    for (int k = 0; k < 128; ++k) {
        float a = ear[k];
        float4 wv0 = *reinterpret_cast<float4*>(&W1s[k * 128 + j0]);
        float4 wv1 = *reinterpret_cast<float4*>(&W1s[k * 128 + j0 + 4]);
        acc[0] += a * wv0.x; acc[1] += a * wv0.y; acc[2] += a * wv0.z; acc[3] += a * wv0.w;
        acc[4] += a * wv1.x; acc[5] += a * wv1.y; acc[6] += a * wv1.z; acc[7] += a * wv1.w;
    }
    short8 hv;
#pragma unroll
    for (int j = 0; j < 8; ++j) hv[j] = (short)f2bf(acc[j] > 0.f ? acc[j] : 0.f);
    *reinterpret_cast<short8*>(h + (size_t)e * 128 + j0) = hv;
}

// ---------------- K2: MFMA GEMM (h@W2T) fused with TP + scatter ----------------
// WG = 256 (4 waves), 32 edges. wave wid: es = wid>>1 (16-edge subtile),
// wt = wid&1 (w-half). A frags in registers; B frags direct from L2 (W2T).
__device__ inline floatx4 gemm16(const short8* a, const unsigned short* bp) {
    floatx4 d = {0.f, 0.f, 0.f, 0.f};
    d = __builtin_amdgcn_mfma_f32_16x16x32_bf16(a[0], *reinterpret_cast<const short8*>(bp),      d, 0, 0, 0);
    d = __builtin_amdgcn_mfma_f32_16x16x32_bf16(a[1], *reinterpret_cast<const short8*>(bp + 32), d, 0, 0, 0);
    d = __builtin_amdgcn_mfma_f32_16x16x32_bf16(a[2], *reinterpret_cast<const short8*>(bp + 64), d, 0, 0, 0);
    d = __builtin_amdgcn_mfma_f32_16x16x32_bf16(a[3], *reinterpret_cast<const short8*>(bp + 96), d, 0, 0, 0);
    return d;
}

__global__ __launch_bounds__(256) void k2_mfma(const unsigned short* __restrict__ h,
                                               const unsigned short* __restrict__ W2T,
                                               const float* __restrict__ b2,
                                               const float* __restrict__ na,
                                               const int* __restrict__ ei,
                                               const float* __restrict__ sh,
                                               float* __restrict__ summed, int E) {
    __shared__ __align__(16) float cA[32 * 32];        // [u][el]
    __shared__ __align__(16) float x0s[32 * 32];       // [u][el]
    __shared__ __align__(16) float x1s[3 * 32 * 32];   // [t][u][el]
    __shared__ __align__(16) float cD[32 * 32];        // [u][el]
    __shared__ float shs[32 * 4];
    __shared__ int   srcs[32];

    const int tid  = threadIdx.x;
    const int e0   = blockIdx.x * 32;
    const int lane = tid & 63;
    const int l15  = lane & 15;
    const int quad = lane >> 4;
    const int wid  = tid >> 6;
    const int es   = wid >> 1;
    const int wt   = wid & 1;

    if (tid < 128) {
        int el = tid >> 2;
        int ee = e0 + el; if (ee >= E) ee = E - 1;
        shs[tid] = sh[(size_t)ee * 4 + (tid & 3)];
    }
    if (tid < 32) {
        int ee = e0 + tid; if (ee >= E) ee = E - 1;
        srcs[tid] = ei[ee];
    }
    for (int idx = tid; idx < 1024; idx += 256) {
        int el = idx >> 5, u = idx & 31;
        int ee = e0 + el; if (ee >= E) ee = E - 1;
        int d = ei[E + ee];
        const float* nar = na + (size_t)d * 128;
        float x0  = nar[u];
        float x10 = nar[32 + u * 3 + 0];
        float x11 = nar[32 + u * 3 + 1];
        float x12 = nar[32 + u * 3 + 2];
        const float* shr = sh + (size_t)ee * 4;
        float s0 = shr[0], s1 = shr[1], s2 = shr[2], s3 = shr[3];
        cA[u * 32 + el]  = x0 * s0;
        x0s[u * 32 + el] = x0;
        x1s[(0 * 32 + u) * 32 + el] = x10;
        x1s[(1 * 32 + u) * 32 + el] = x11;
        x1s[(2 * 32 + u) * 32 + el] = x12;
        cD[u * 32 + el]  = IS3 * (x10 * s1 + x11 * s2 + x12 * s3);
    }

    short8 afrag[4];
    {
        int ea_ = e0 + es * 16 + l15; if (ea_ >= E) ea_ = E - 1;
        const unsigned short* ap = h + ((size_t)ea_ << 7) + (quad << 3);
        afrag[0] = *reinterpret_cast<const short8*>(ap);
        afrag[1] = *reinterpret_cast<const short8*>(ap + 32);
        afrag[2] = *reinterpret_cast<const short8*>(ap + 64);
        afrag[3] = *reinterpret_cast<const short8*>(ap + 96);
    }
    __syncthreads();

    float acc0[4] = {}, accB[4] = {}, accC0[4] = {}, accC1[4] = {}, accC2[4] = {};
    const int elbase = es * 16 + quad * 4;

    // b = 0: wA -> acc0 += cA * (dot + b2)
    for (int u = 0; u < 32; ++u) {
        const int col0 = u * 32 + wt * 16;
        floatx4 d = gemm16(afrag, W2T + ((size_t)(col0 + l15) << 7) + (quad << 3));
        const float b2v = b2[col0 + l15];
        const float4 cf = *reinterpret_cast<const float4*>(&cA[u * 32 + elbase]);
        acc0[0] += cf.x * (d[0] + b2v);
        acc0[1] += cf.y * (d[1] + b2v);
        acc0[2] += cf.z * (d[2] + b2v);
        acc0[3] += cf.w * (d[3] + b2v);
    }
    // b = 1: wB -> accB += x0 * (dot + b2)
    for (int u = 0; u < 32; ++u) {
        const int col0 = 1024 + u * 32 + wt * 16;
        floatx4 d = gemm16(afrag, W2T + ((size_t)(col0 + l15) << 7) + (quad << 3));
        const float b2v = b2[col0 + l15];
        const float4 cf = *reinterpret_cast<const float4*>(&x0s[u * 32 + elbase]);
        accB[0] += cf.x * (d[0] + b2v);
        accB[1] += cf.y * (d[1] + b2v);
        accB[2] += cf.z * (d[2] + b2v);
        accB[3] += cf.w * (d[3] + b2v);
    }
    // b = 2: wC -> accC[t] += x1[t] * (dot + b2)
    for (int u = 0; u < 32; ++u) {
        const int col0 = 2048 + u * 32 + wt * 16;
        floatx4 d = gemm16(afrag, W2T + ((size_t)(col0 + l15) << 7) + (quad << 3));
        const float b2v = b2[col0 + l15];
        float4 v;
        v.x = d[0] + b2v; v.y = d[1] + b2v; v.z = d[2] + b2v; v.w = d[3] + b2v;
        const float4 c0 = *reinterpret_cast<const float4*>(&x1s[(0 * 32 + u) * 32 + elbase]);
        const float4 c1 = *reinterpret_cast<const float4*>(&x1s[(1 * 32 + u) * 32 + elbase]);
        const float4 c2 = *reinterpret_cast<const float4*>(&x1s[(2 * 32 + u) * 32 + elbase]);
        accC0[0] += c0.x * v.x; accC0[1] += c0.y * v.y; accC0[2] += c0.z * v.z; accC0[3] += c0.w * v.w;
        accC1[0] += c1.x * v.x; accC1[1] += c1.y * v.y; accC1[2] += c1.z * v.z; accC1[3] += c1.w * v.w;
        accC2[0] += c2.x * v.x; accC2[1] += c2.y * v.y; accC2[2] += c2.z * v.z; accC2[3] += c2.w * v.w;
    }
    // b = 3: wD -> acc0 += cD * (dot + b2)   (cD includes IS3)
    for (int u = 0; u < 32; ++u) {
        const int col0 = 3072 + u * 32 + wt * 16;
        floatx4 d = gemm16(afrag, W2T + ((size_t)(col0 + l15) << 7) + (quad << 3));
        const float b2v = b2[col0 + l15];
        const float4 cf = *reinterpret_cast<const float4*>(&cD[u * 32 + elbase]);
        acc0[0] += cf.x * (d[0] + b2v);
        acc0[1] += cf.y * (d[1] + b2v);
        acc0[2] += cf.z * (d[2] + b2v);
        acc0[3] += cf.w * (d[3] + b2v);
    }

    // epilogue: scatter-add into summed
    const int w = wt * 16 + l15;
#pragma unroll
    for (int r = 0; r < 4; ++r) {
        int el = elbase + r;
        if (e0 + el >= E) continue;
        int s = srcs[el];
        float s0 = shs[el * 4 + 0], s1 = shs[el * 4 + 1];
        float s2 = shs[el * 4 + 2], s3 = shs[el * 4 + 3];
        float* sp = summed + ((size_t)s << 7);
        atomicAdd(sp + w, PNRM * acc0[r]);
        atomicAdd(sp + 32 + w * 3 + 0, PNRM * IS3 * (s1 * accB[r] + s0 * accC0[r]));
        atomicAdd(sp + 32 + w * 3 + 1, PNRM * IS3 * (s2 * accB[r] + s0 * accC1[r]));
        atomicAdd(sp + 32 + w * 3 + 2, PNRM * IS3 * (s3 * accB[r] + s0 * accC2[r]));
    }
}

// ---------------- K4: mean + residual, BN stats ----------------
__global__ __launch_bounds__(256) void k4_pre(float* __restrict__ pre,
                                              const float* __restrict__ counts,
                                              const float* __restrict__ na,
                                              float* __restrict__ stats, int N) {
    __shared__ float bns[96];
    const int tid = threadIdx.x;
    if (tid < 96) bns[tid] = 0.f;
    __syncthreads();
    size_t idx = (size_t)blockIdx.x * 256 + tid;
    if (idx < (size_t)N * 128) {
        int n = (int)(idx >> 7), o = (int)(idx & 127);
        float c = counts[n];
        c = c > 1.f ? c : 1.f;
        float v = pre[idx] / c + na[idx];
        pre[idx] = v;
        if (o < 32) {
            atomicAdd(&bns[o], v);
            atomicAdd(&bns[32 + o], v * v);
        } else {
            atomicAdd(&bns[64 + (o - 32) / 3], v * v);
        }
    }
    __syncthreads();
    if (tid < 96) atomicAdd(&stats[tid], bns[tid]);
}

// ---------------- K5: apply batch norm ----------------
__global__ __launch_bounds__(256) void k5_bn(const float* __restrict__ pre,
                                             const float* __restrict__ stats,
                                             const float* __restrict__ bnw,
                                             const float* __restrict__ bnb,
                                             float* __restrict__ out, int N) {
    size_t idx = (size_t)blockIdx.x * 256 + threadIdx.x;
    if (idx >= (size_t)N * 128) return;
    int o = (int)(idx & 127);
    float v = pre[idx];
    float invN = 1.f / (float)N;
    if (o < 32) {
        float m   = stats[o] * invN;
        float var = stats[32 + o] * invN - m * m;
        out[idx] = (v - m) * rsqrtf(var + EPSV) * bnw[o] + bnb[o];
    } else {
        int j = (o - 32) / 3;
        float vn = rsqrtf(stats[64 + j] * invN * (1.f / 3.f) + EPSV);
        out[idx] = v * vn * bnw[32 + j];
    }
}

extern "C" void kernel_launch(void* const* d_in, const int* in_sizes, int n_in,
                              void* d_out, int out_size, void* d_ws, size_t ws_size,
                              hipStream_t stream) {
    const float* node_attr  = (const float*)d_in[0];
    const int*   edge_index = (const int*)d_in[1];
    const float* edge_attr  = (const float*)d_in[2];
    const float* edge_sh    = (const float*)d_in[3];
    const float* W1  = (const float*)d_in[4];
    const float* b1  = (const float*)d_in[5];
    const float* W2  = (const float*)d_in[6];
    const float* b2  = (const float*)d_in[7];
    const float* bnw = (const float*)d_in[8];
    const float* bnb = (const float*)d_in[9];

    const int N = in_sizes[0] / 128;
    const int E = in_sizes[1] / 2;

    float* ws     = (float*)d_ws;
    float* summed = ws;                           // N*128 f32
    float* counts = summed + (size_t)N * 128;     // N f32
    float* stats  = counts + N;                   // 96 f32
    unsigned short* h   = (unsigned short*)(stats + 96);   // E*128 bf16
    unsigned short* W2T = h + (size_t)E * 128;             // 4096*128 bf16

    size_t zbytes = ((size_t)N * 128 + (size_t)N + 96) * sizeof(float);
    hipMemsetAsync(summed, 0, zbytes, stream);

    k0_w2t<<<dim3(128, 4), 256, 0, stream>>>(W2, W2T);
    k1_fc<<<(E + 15) / 16, 256, 0, stream>>>(edge_attr, W1, b1, edge_index, h, counts, E);
    k2_mfma<<<(E + 31) / 32, 256, 0, stream>>>(h, W2T, b2, node_attr, edge_index,
                                               edge_sh, summed, E);
    size_t ntot = (size_t)N * 128;
    k4_pre<<<(int)((ntot + 255) / 256), 256, 0, stream>>>(summed, counts,
                                                          node_attr, stats, N);
    k5_bn<<<(int)((ntot + 255) / 256), 256, 0, stream>>>(summed, stats, bnw, bnb,
                                                         (float*)d_out, N);
}

// Round 3
// 451.342 us; speedup vs baseline: 8.1633x; 4.4120x over previous
//
#include <hip/hip_runtime.h>
#include <math.h>

#define EPSV 1e-5f
#define IS3  0.57735026918962576f   // 1/sqrt(3)
#define PNRM 0.125f                 // 1/sqrt(2*32)

typedef __attribute__((ext_vector_type(8)))  short  short8;
typedef __attribute__((ext_vector_type(16))) float  floatx16;

static __device__ inline unsigned short f2bf(float f) {
    unsigned int u = __float_as_uint(f);
    return (unsigned short)((u + 0x7fff + ((u >> 16) & 1)) >> 16);  // RNE
}
static __device__ inline float bflo(unsigned int u) { return __uint_as_float(u << 16); }
static __device__ inline float bfhi(unsigned int u) { return __uint_as_float(u & 0xffff0000u); }

// async global->LDS, 16B per lane; lds dest = uniform base + lane*16 (HW adds it)
#define GLD16(gp, lp) __builtin_amdgcn_global_load_lds( \
    (const __attribute__((address_space(1))) unsigned int*)(gp), \
    (__attribute__((address_space(3))) unsigned int*)(lp), 16, 0, 0)

// ---- K0: f32 [128 x NC] -> bf16 swizzled col-tiles: tile=col/32,
//      addr(short) = tile*4096 + (k>>3)*256 + (col&31)*8 + (k&7)
__global__ __launch_bounds__(256) void k0_sw(const float* __restrict__ src,
                                             unsigned short* __restrict__ dst,
                                             int total, int ncShift, int ncMask) {
    int i = blockIdx.x * 256 + threadIdx.x;
    if (i >= total) return;
    int k = i >> ncShift, c = i & ncMask;
    dst[(size_t)(c >> 5) * 4096 + (k >> 3) * 256 + (c & 31) * 8 + (k & 7)] = f2bf(src[i]);
}

// ---- K1: h = relu(ea @ W1 + b1) via MFMA 32x32x16; writes h row-major bf16.
// 256 thr / 4 waves, 128 edges per WG. Also accumulates per-src edge counts.
__global__ __launch_bounds__(256) void k1_fc(const float* __restrict__ ea,
                                             const unsigned short* __restrict__ W1T,
                                             const float* __restrict__ b1,
                                             const int* __restrict__ ei,
                                             unsigned short* __restrict__ h,
                                             float* __restrict__ counts, int E) {
    __shared__ __align__(16) unsigned short W1s[16384];  // 32 KB, swizzled tiles
    const int tid = threadIdx.x, lane = tid & 63, wv = tid >> 6;
    const int half = lane >> 5, col = lane & 31;
    const int e0 = blockIdx.x * 128;

    if (tid < 128) { int e = e0 + tid; if (e < E) atomicAdd(&counts[ei[e]], 1.0f); }

#pragma unroll
    for (int q = 0; q < 8; ++q) {
        int chunk = wv * 8 + q;
        GLD16((const char*)W1T + chunk * 1024 + lane * 16, (char*)W1s + chunk * 1024);
    }

    int e = e0 + wv * 32 + col; if (e >= E) e = E - 1;
    short8 afr[8];
#pragma unroll
    for (int c = 0; c < 8; ++c) {
        const float4* p = (const float4*)(ea + (size_t)e * 128 + c * 16 + half * 8);
        float4 f0 = p[0], f1 = p[1];
        short8 v;
        v[0] = (short)f2bf(f0.x); v[1] = (short)f2bf(f0.y);
        v[2] = (short)f2bf(f0.z); v[3] = (short)f2bf(f0.w);
        v[4] = (short)f2bf(f1.x); v[5] = (short)f2bf(f1.y);
        v[6] = (short)f2bf(f1.z); v[7] = (short)f2bf(f1.w);
        afr[c] = v;
    }
    __syncthreads();

#pragma unroll
    for (int jt = 0; jt < 4; ++jt) {
        floatx16 d = {0,0,0,0,0,0,0,0,0,0,0,0,0,0,0,0};
#pragma unroll
        for (int c = 0; c < 8; ++c) {
            short8 bf = *(const short8*)((const char*)W1s + jt * 8192 + (2 * c + half) * 512 + col * 16);
            d = __builtin_amdgcn_mfma_f32_32x32x16_bf16(afr[c], bf, d, 0, 0, 0);
        }
        int j = jt * 32 + col;
        float b1v = b1[j];
#pragma unroll
        for (int reg = 0; reg < 16; ++reg) {
            int r = (reg & 3) + 8 * (reg >> 2) + 4 * half;
            int er = e0 + wv * 32 + r;
            if (er < E) {
                float v = d[reg] + b1v;
                v = v > 0.f ? v : 0.f;
                h[(size_t)er * 128 + j] = f2bf(v);
            }
        }
    }
}

// ---- K2: MFMA 32x32x16 GEMM (h @ W2) fused with TP contraction + scatter.
// 256 thr / 4 waves, 64 edges/WG. wave = (esub = wv&1) x (u-stream = wv>>1).
// B tiles (8 KB) double-buffered via global_load_lds; A frags in registers.
__global__ __launch_bounds__(256, 2) void k2_mfma(const unsigned short* __restrict__ h,
                                                  const unsigned short* __restrict__ W2T,
                                                  const float* __restrict__ b2,
                                                  const float* __restrict__ na,
                                                  const int* __restrict__ ei,
                                                  const float* __restrict__ sh,
                                                  float* __restrict__ summed, int E) {
    __shared__ __align__(16) unsigned short As[8192];      // 16 KB: 2 edge-groups
    __shared__ __align__(16) unsigned short Bs[2][8192];   // 32 KB: dbuf x 2 tiles
    __shared__ __align__(16) unsigned short Ct[6][2048];   // 24 KB: coef tables [u*64+el]
    __shared__ __align__(16) float shs[256];               // [el][4]
    __shared__ int srcs[64];

    const int tid = threadIdx.x, lane = tid & 63, wv = tid >> 6;
    const int half = lane >> 5, col = lane & 31;
    const int ust = wv >> 1, esub = wv & 1;
    const int e0 = blockIdx.x * 64;

    if (tid < 64) {
        int e = e0 + tid; int ec = e < E ? e : E - 1;
        srcs[tid] = ei[ec];
        float4 s = *(const float4*)(sh + (size_t)ec * 4);
        *(float4*)&shs[tid * 4] = s;
    }

    // coefficient tables (bf16), layout [u][el]
    for (int idx = tid; idx < 2048; idx += 256) {
        int el = idx & 63, u = idx >> 6;
        int e = e0 + el; int ec = e < E ? e : E - 1;
        int dn = ei[E + ec];
        const float* nar = na + (size_t)dn * 128;
        float x0  = nar[u];
        float x10 = nar[32 + u * 3], x11 = nar[33 + u * 3], x12 = nar[34 + u * 3];
        const float* shr = sh + (size_t)ec * 4;
        float s0 = shr[0], s1 = shr[1], s2 = shr[2], s3 = shr[3];
        int o = u * 64 + el;
        Ct[0][o] = f2bf(x0 * s0);
        Ct[1][o] = f2bf(x0);
        Ct[2][o] = f2bf(x10);
        Ct[3][o] = f2bf(x11);
        Ct[4][o] = f2bf(x12);
        Ct[5][o] = f2bf(IS3 * (x10 * s1 + x11 * s2 + x12 * s3));
    }

    // stage A (h-tile, swizzled into frag order), 16 KB
#pragma unroll
    for (int q = 0; q < 4; ++q) {
        int t = wv * 4 + q;                 // 0..15
        int g = t >> 3;
        int jj = (t & 7) * 64 + lane;       // chunk in group [0,512)
        int e = e0 + g * 32 + (jj & 31); int ec = e < E ? e : E - 1;
        GLD16((const char*)h + (size_t)ec * 256 + (jj >> 5) * 16,
              (char*)As + g * 8192 + (t & 7) * 1024);
    }
    // stage B pair 0 (tiles 0,1) -> Bs[0], 16 KB linear
#pragma unroll
    for (int q = 0; q < 4; ++q) {
        int chunk = wv * 4 + q;
        GLD16((const char*)W2T + chunk * 1024 + lane * 16, (char*)Bs[0] + chunk * 1024);
    }
    __syncthreads();

    short8 afr[8];
#pragma unroll
    for (int c = 0; c < 8; ++c)
        afr[c] = *(const short8*)((const char*)As + esub * 8192 + (2 * c + half) * 512 + col * 16);

    float acc0[16] = {}, accB[16] = {}, accC0[16] = {}, accC1[16] = {}, accC2[16] = {};

    for (int p = 0; p < 64; ++p) {
        if (p < 63) {
#pragma unroll
            for (int q = 0; q < 4; ++q) {
                int chunk = wv * 4 + q;
                GLD16((const char*)W2T + (p + 1) * 16384 + chunk * 1024 + lane * 16,
                      (char*)Bs[(p + 1) & 1] + chunk * 1024);
            }
        }
        const int ct = 2 * p + ust;          // column tile = b*32 + u
        const int b = ct >> 5, u = ct & 31;
        const char* bb = (const char*)Bs[p & 1] + ust * 8192;

        floatx16 d = {0,0,0,0,0,0,0,0,0,0,0,0,0,0,0,0};
#pragma unroll
        for (int c = 0; c < 8; ++c) {
            short8 bf = *(const short8*)(bb + (2 * c + half) * 512 + col * 16);
            d = __builtin_amdgcn_mfma_f32_32x32x16_bf16(afr[c], bf, d, 0, 0, 0);
        }
        float b2v = b2[ct * 32 + col];

        const int elb0 = esub * 32 + half * 4;
        if (b == 0 || b == 3) {
            const unsigned short* tb = Ct[b == 0 ? 0 : 5];
#pragma unroll
            for (int q = 0; q < 4; ++q) {
                uint2 cv = *(const uint2*)&tb[u * 64 + elb0 + q * 8];
                acc0[q * 4 + 0] += bflo(cv.x) * (d[q * 4 + 0] + b2v);
                acc0[q * 4 + 1] += bfhi(cv.x) * (d[q * 4 + 1] + b2v);
                acc0[q * 4 + 2] += bflo(cv.y) * (d[q * 4 + 2] + b2v);
                acc0[q * 4 + 3] += bfhi(cv.y) * (d[q * 4 + 3] + b2v);
            }
        } else if (b == 1) {
#pragma unroll
            for (int q = 0; q < 4; ++q) {
                uint2 cv = *(const uint2*)&Ct[1][u * 64 + elb0 + q * 8];
                accB[q * 4 + 0] += bflo(cv.x) * (d[q * 4 + 0] + b2v);
                accB[q * 4 + 1] += bfhi(cv.x) * (d[q * 4 + 1] + b2v);
                accB[q * 4 + 2] += bflo(cv.y) * (d[q * 4 + 2] + b2v);
                accB[q * 4 + 3] += bfhi(cv.y) * (d[q * 4 + 3] + b2v);
            }
        } else {  // b == 2
#pragma unroll
            for (int q = 0; q < 4; ++q) {
                uint2 c0 = *(const uint2*)&Ct[2][u * 64 + elb0 + q * 8];
                uint2 c1 = *(const uint2*)&Ct[3][u * 64 + elb0 + q * 8];
                uint2 c2 = *(const uint2*)&Ct[4][u * 64 + elb0 + q * 8];
#pragma unroll
                for (int rr = 0; rr < 4; ++rr) {
                    float v = d[q * 4 + rr] + b2v;
                    unsigned int w0 = (rr & 1) ? 0 : 1;  // lo/hi selector below
                    float f0 = (rr == 0) ? bflo(c0.x) : (rr == 1) ? bfhi(c0.x) : (rr == 2) ? bflo(c0.y) : bfhi(c0.y);
                    float f1 = (rr == 0) ? bflo(c1.x) : (rr == 1) ? bfhi(c1.x) : (rr == 2) ? bflo(c1.y) : bfhi(c1.y);
                    float f2 = (rr == 0) ? bflo(c2.x) : (rr == 1) ? bfhi(c2.x) : (rr == 2) ? bflo(c2.y) : bfhi(c2.y);
                    (void)w0;
                    accC0[q * 4 + rr] += f0 * v;
                    accC1[q * 4 + rr] += f1 * v;
                    accC2[q * 4 + rr] += f2 * v;
                }
            }
        }
        __syncthreads();
    }

    // epilogue: both u-streams atomically add their partial contractions
#pragma unroll
    for (int q = 0; q < 4; ++q) {
        int elb = esub * 32 + q * 8 + half * 4;
#pragma unroll
        for (int rr = 0; rr < 4; ++rr) {
            int el = elb + rr, e = e0 + el;
            if (e >= E) continue;
            int reg = q * 4 + rr;
            int s = srcs[el];
            float4 sv = *(const float4*)&shs[el * 4];
            float* sp = summed + (size_t)s * 128;
            atomicAdd(sp + col, PNRM * acc0[reg]);
            atomicAdd(sp + 32 + col * 3 + 0, PNRM * IS3 * (sv.y * accB[reg] + sv.x * accC0[reg]));
            atomicAdd(sp + 32 + col * 3 + 1, PNRM * IS3 * (sv.z * accB[reg] + sv.x * accC1[reg]));
            atomicAdd(sp + 32 + col * 3 + 2, PNRM * IS3 * (sv.w * accB[reg] + sv.x * accC2[reg]));
        }
    }
}

// ---- K4: mean + residual, BN stats ----
__global__ __launch_bounds__(256) void k4_pre(float* __restrict__ pre,
                                              const float* __restrict__ counts,
                                              const float* __restrict__ na,
                                              float* __restrict__ stats, int N) {
    __shared__ float bns[96];
    const int tid = threadIdx.x;
    if (tid < 96) bns[tid] = 0.f;
    __syncthreads();
    size_t idx = (size_t)blockIdx.x * 256 + tid;
    if (idx < (size_t)N * 128) {
        int n = (int)(idx >> 7), o = (int)(idx & 127);
        float c = counts[n];
        c = c > 1.f ? c : 1.f;
        float v = pre[idx] / c + na[idx];
        pre[idx] = v;
        if (o < 32) {
            atomicAdd(&bns[o], v);
            atomicAdd(&bns[32 + o], v * v);
        } else {
            atomicAdd(&bns[64 + (o - 32) / 3], v * v);
        }
    }
    __syncthreads();
    if (tid < 96) atomicAdd(&stats[tid], bns[tid]);
}

// ---- K5: apply batch norm ----
__global__ __launch_bounds__(256) void k5_bn(const float* __restrict__ pre,
                                             const float* __restrict__ stats,
                                             const float* __restrict__ bnw,
                                             const float* __restrict__ bnb,
                                             float* __restrict__ out, int N) {
    size_t idx = (size_t)blockIdx.x * 256 + threadIdx.x;
    if (idx >= (size_t)N * 128) return;
    int o = (int)(idx & 127);
    float v = pre[idx];
    float invN = 1.f / (float)N;
    if (o < 32) {
        float m   = stats[o] * invN;
        float var = stats[32 + o] * invN - m * m;
        out[idx] = (v - m) * rsqrtf(var + EPSV) * bnw[o] + bnb[o];
    } else {
        int j = (o - 32) / 3;
        float vn = rsqrtf(stats[64 + j] * invN * (1.f / 3.f) + EPSV);
        out[idx] = v * vn * bnw[32 + j];
    }
}

extern "C" void kernel_launch(void* const* d_in, const int* in_sizes, int n_in,
                              void* d_out, int out_size, void* d_ws, size_t ws_size,
                              hipStream_t stream) {
    const float* node_attr  = (const float*)d_in[0];
    const int*   edge_index = (const int*)d_in[1];
    const float* edge_attr  = (const float*)d_in[2];
    const float* edge_sh    = (const float*)d_in[3];
    const float* W1  = (const float*)d_in[4];
    const float* b1  = (const float*)d_in[5];
    const float* W2  = (const float*)d_in[6];
    const float* b2  = (const float*)d_in[7];
    const float* bnw = (const float*)d_in[8];
    const float* bnb = (const float*)d_in[9];

    const int N = in_sizes[0] / 128;
    const int E = in_sizes[1] / 2;

    float* ws     = (float*)d_ws;
    float* summed = ws;                           // N*128 f32
    float* counts = summed + (size_t)N * 128;     // N f32
    float* stats  = counts + N;                   // 96 f32
    unsigned short* h   = (unsigned short*)(stats + 96);   // E*128 bf16
    unsigned short* W2T = h + (size_t)E * 128;             // 128*4096 bf16 swizzled
    unsigned short* W1T = W2T + (size_t)128 * 4096;        // 128*128 bf16 swizzled

    size_t zbytes = ((size_t)N * 128 + (size_t)N + 96) * sizeof(float);
    hipMemsetAsync(summed, 0, zbytes, stream);

    k0_sw<<<(128 * 4096 + 255) / 256, 256, 0, stream>>>(W2, W2T, 128 * 4096, 12, 4095);
    k0_sw<<<(128 * 128 + 255) / 256, 256, 0, stream>>>(W1, W1T, 128 * 128, 7, 127);
    k1_fc<<<(E + 127) / 128, 256, 0, stream>>>(edge_attr, W1T, b1, edge_index, h, counts, E);
    k2_mfma<<<(E + 63) / 64, 256, 0, stream>>>(h, W2T, b2, node_attr, edge_index,
                                               edge_sh, summed, E);
    size_t ntot = (size_t)N * 128;
    k4_pre<<<(int)((ntot + 255) / 256), 256, 0, stream>>>(summed, counts,
                                                          node_attr, stats, N);
    k5_bn<<<(int)((ntot + 255) / 256), 256, 0, stream>>>(summed, stats, bnw, bnb,
                                                         (float*)d_out, N);
}

// Round 4
// 317.398 us; speedup vs baseline: 11.6082x; 1.4220x over previous
//
#include <hip/hip_runtime.h>
#include <math.h>

#define EPSV 1e-5f
#define IS3  0.57735026918962576f   // 1/sqrt(3)
#define PNRM 0.125f                 // 1/sqrt(2*32)

typedef __attribute__((ext_vector_type(8)))  short  short8;
typedef __attribute__((ext_vector_type(16))) float  floatx16;

static __device__ inline unsigned short f2bf(float f) {
    unsigned int u = __float_as_uint(f);
    return (unsigned short)((u + 0x7fff + ((u >> 16) & 1)) >> 16);  // RNE
}
static __device__ inline float bflo(unsigned int u) { return __uint_as_float(u << 16); }
static __device__ inline float bfhi(unsigned int u) { return __uint_as_float(u & 0xffff0000u); }

// async global->LDS, 16B per lane; lds dest = uniform base + lane*16 (HW adds it)
#define GLD16(gp, lp) __builtin_amdgcn_global_load_lds( \
    (const __attribute__((address_space(1))) unsigned int*)(gp), \
    (__attribute__((address_space(3))) unsigned int*)(lp), 16, 0, 0)

// ---- K0: f32 [128 x NC] -> bf16 swizzled col-tiles: tile=col/32,
//      addr(short) = tile*4096 + (k>>3)*256 + (col&31)*8 + (k&7)
__global__ __launch_bounds__(256) void k0_sw(const float* __restrict__ src,
                                             unsigned short* __restrict__ dst,
                                             int total, int ncShift, int ncMask) {
    int i = blockIdx.x * 256 + threadIdx.x;
    if (i >= total) return;
    int k = i >> ncShift, c = i & ncMask;
    dst[(size_t)(c >> 5) * 4096 + (k >> 3) * 256 + (c & 31) * 8 + (k & 7)] = f2bf(src[i]);
}

// ---- K1: h = relu(ea @ W1 + b1) via MFMA 32x32x16; writes h row-major bf16.
// 256 thr / 4 waves, 128 edges per WG. Also counts out-degrees (int).
__global__ __launch_bounds__(256) void k1_fc(const float* __restrict__ ea,
                                             const unsigned short* __restrict__ W1T,
                                             const float* __restrict__ b1,
                                             const int* __restrict__ ei,
                                             unsigned short* __restrict__ h,
                                             int* __restrict__ deg, int E) {
    __shared__ __align__(16) unsigned short W1s[16384];  // 32 KB, swizzled tiles
    const int tid = threadIdx.x, lane = tid & 63, wv = tid >> 6;
    const int half = lane >> 5, col = lane & 31;
    const int e0 = blockIdx.x * 128;

    if (tid < 128) { int e = e0 + tid; if (e < E) atomicAdd(&deg[ei[e]], 1); }

#pragma unroll
    for (int q = 0; q < 8; ++q) {
        int chunk = wv * 8 + q;
        GLD16((const char*)W1T + chunk * 1024 + lane * 16, (char*)W1s + chunk * 1024);
    }

    int e = e0 + wv * 32 + col; if (e >= E) e = E - 1;
    short8 afr[8];
#pragma unroll
    for (int c = 0; c < 8; ++c) {
        const float4* p = (const float4*)(ea + (size_t)e * 128 + c * 16 + half * 8);
        float4 f0 = p[0], f1 = p[1];
        short8 v;
        v[0] = (short)f2bf(f0.x); v[1] = (short)f2bf(f0.y);
        v[2] = (short)f2bf(f0.z); v[3] = (short)f2bf(f0.w);
        v[4] = (short)f2bf(f1.x); v[5] = (short)f2bf(f1.y);
        v[6] = (short)f2bf(f1.z); v[7] = (short)f2bf(f1.w);
        afr[c] = v;
    }
    __syncthreads();

#pragma unroll
    for (int jt = 0; jt < 4; ++jt) {
        floatx16 d = {0,0,0,0,0,0,0,0,0,0,0,0,0,0,0,0};
#pragma unroll
        for (int c = 0; c < 8; ++c) {
            short8 bf = *(const short8*)((const char*)W1s + jt * 8192 + (2 * c + half) * 512 + col * 16);
            d = __builtin_amdgcn_mfma_f32_32x32x16_bf16(afr[c], bf, d, 0, 0, 0);
        }
        int j = jt * 32 + col;
        float b1v = b1[j];
#pragma unroll
        for (int reg = 0; reg < 16; ++reg) {
            int r = (reg & 3) + 8 * (reg >> 2) + 4 * half;
            int er = e0 + wv * 32 + r;
            if (er < E) {
                float v = d[reg] + b1v;
                v = v > 0.f ? v : 0.f;
                h[(size_t)er * 128 + j] = f2bf(v);
            }
        }
    }
}

// ---- K2: MFMA 32x32x16 GEMM (h @ W2) fused with TP; plain stores to tp ----
__global__ __launch_bounds__(256, 2) void k2_mfma(const unsigned short* __restrict__ h,
                                                  const unsigned short* __restrict__ W2T,
                                                  const float* __restrict__ b2,
                                                  const float* __restrict__ na,
                                                  const int* __restrict__ ei,
                                                  const float* __restrict__ sh,
                                                  float* __restrict__ tp, int E) {
    __shared__ __align__(16) char smem[74752];
    unsigned short* As  = (unsigned short*)smem;              // 16384 B
    unsigned short* Bs0 = (unsigned short*)(smem + 16384);    // 16384 B
    unsigned short* Bs1 = (unsigned short*)(smem + 32768);    // 16384 B
    unsigned short* Ctb = (unsigned short*)(smem + 49152);    // 6*4096 B
    float* shs = (float*)(smem + 73728);                      // 64*4 f32
    float* red = (float*)smem;                                // epilogue alias 40960 B

    const int tid = threadIdx.x, lane = tid & 63, wv = tid >> 6;
    const int half = lane >> 5, col = lane & 31;
    const int ust = wv >> 1, esub = wv & 1;
    const int e0 = blockIdx.x * 64;

    if (tid < 64) {
        int e = e0 + tid; int ec = e < E ? e : E - 1;
        float4 s = *(const float4*)(sh + (size_t)ec * 4);
        *(float4*)&shs[tid * 4] = s;
    }

    // coefficient tables (bf16), layout [u][el]
    for (int idx = tid; idx < 2048; idx += 256) {
        int el = idx & 63, u = idx >> 6;
        int e = e0 + el; int ec = e < E ? e : E - 1;
        int dn = ei[E + ec];
        const float* nar = na + (size_t)dn * 128;
        float x0  = nar[u];
        float x10 = nar[32 + u * 3], x11 = nar[33 + u * 3], x12 = nar[34 + u * 3];
        const float* shr = sh + (size_t)ec * 4;
        float s0 = shr[0], s1 = shr[1], s2 = shr[2], s3 = shr[3];
        int o = u * 64 + el;
        Ctb[0 * 2048 + o] = f2bf(x0 * s0);
        Ctb[1 * 2048 + o] = f2bf(x0);
        Ctb[2 * 2048 + o] = f2bf(x10);
        Ctb[3 * 2048 + o] = f2bf(x11);
        Ctb[4 * 2048 + o] = f2bf(x12);
        Ctb[5 * 2048 + o] = f2bf(IS3 * (x10 * s1 + x11 * s2 + x12 * s3));
    }

    // stage A (h-tile, swizzled into frag order), 16 KB
#pragma unroll
    for (int q = 0; q < 4; ++q) {
        int t = wv * 4 + q;                 // 0..15
        int g = t >> 3;
        int jj = (t & 7) * 64 + lane;
        int e = e0 + g * 32 + (jj & 31); int ec = e < E ? e : E - 1;
        GLD16((const char*)h + (size_t)ec * 256 + (jj >> 5) * 16,
              (char*)As + g * 8192 + (t & 7) * 1024);
    }
    // stage B pair 0 -> Bs0
#pragma unroll
    for (int q = 0; q < 4; ++q) {
        int chunk = wv * 4 + q;
        GLD16((const char*)W2T + chunk * 1024 + lane * 16, (char*)Bs0 + chunk * 1024);
    }
    __syncthreads();

    short8 afr[8];
#pragma unroll
    for (int c = 0; c < 8; ++c)
        afr[c] = *(const short8*)((const char*)As + esub * 8192 + (2 * c + half) * 512 + col * 16);

    float acc0[16] = {}, accB[16] = {}, accC0[16] = {}, accC1[16] = {}, accC2[16] = {};

    for (int p = 0; p < 64; ++p) {
        if (p < 63) {
            char* dst = ((p + 1) & 1) ? (char*)Bs1 : (char*)Bs0;
#pragma unroll
            for (int q = 0; q < 4; ++q) {
                int chunk = wv * 4 + q;
                GLD16((const char*)W2T + (p + 1) * 16384 + chunk * 1024 + lane * 16,
                      dst + chunk * 1024);
            }
        }
        const int ct = 2 * p + ust;          // column tile = b*32 + u
        const int b = ct >> 5, u = ct & 31;
        const char* bb = ((p & 1) ? (const char*)Bs1 : (const char*)Bs0) + ust * 8192;

        floatx16 d = {0,0,0,0,0,0,0,0,0,0,0,0,0,0,0,0};
#pragma unroll
        for (int c = 0; c < 8; ++c) {
            short8 bf = *(const short8*)(bb + (2 * c + half) * 512 + col * 16);
            d = __builtin_amdgcn_mfma_f32_32x32x16_bf16(afr[c], bf, d, 0, 0, 0);
        }
        float b2v = b2[ct * 32 + col];

        const int elb0 = esub * 32 + half * 4;
        if (b == 0 || b == 3) {
            const unsigned short* tb = Ctb + (b == 0 ? 0 : 5) * 2048;
#pragma unroll
            for (int q = 0; q < 4; ++q) {
                uint2 cv = *(const uint2*)&tb[u * 64 + elb0 + q * 8];
                acc0[q * 4 + 0] += bflo(cv.x) * (d[q * 4 + 0] + b2v);
                acc0[q * 4 + 1] += bfhi(cv.x) * (d[q * 4 + 1] + b2v);
                acc0[q * 4 + 2] += bflo(cv.y) * (d[q * 4 + 2] + b2v);
                acc0[q * 4 + 3] += bfhi(cv.y) * (d[q * 4 + 3] + b2v);
            }
        } else if (b == 1) {
#pragma unroll
            for (int q = 0; q < 4; ++q) {
                uint2 cv = *(const uint2*)&Ctb[1 * 2048 + u * 64 + elb0 + q * 8];
                accB[q * 4 + 0] += bflo(cv.x) * (d[q * 4 + 0] + b2v);
                accB[q * 4 + 1] += bfhi(cv.x) * (d[q * 4 + 1] + b2v);
                accB[q * 4 + 2] += bflo(cv.y) * (d[q * 4 + 2] + b2v);
                accB[q * 4 + 3] += bfhi(cv.y) * (d[q * 4 + 3] + b2v);
            }
        } else {  // b == 2
#pragma unroll
            for (int q = 0; q < 4; ++q) {
                uint2 c0 = *(const uint2*)&Ctb[2 * 2048 + u * 64 + elb0 + q * 8];
                uint2 c1 = *(const uint2*)&Ctb[3 * 2048 + u * 64 + elb0 + q * 8];
                uint2 c2 = *(const uint2*)&Ctb[4 * 2048 + u * 64 + elb0 + q * 8];
#pragma unroll
                for (int rr = 0; rr < 4; ++rr) {
                    float v = d[q * 4 + rr] + b2v;
                    float f0 = (rr == 0) ? bflo(c0.x) : (rr == 1) ? bfhi(c0.x) : (rr == 2) ? bflo(c0.y) : bfhi(c0.y);
                    float f1 = (rr == 0) ? bflo(c1.x) : (rr == 1) ? bfhi(c1.x) : (rr == 2) ? bflo(c1.y) : bfhi(c1.y);
                    float f2 = (rr == 0) ? bflo(c2.x) : (rr == 1) ? bfhi(c2.x) : (rr == 2) ? bflo(c2.y) : bfhi(c2.y);
                    accC0[q * 4 + rr] += f0 * v;
                    accC1[q * 4 + rr] += f1 * v;
                    accC2[q * 4 + rr] += f2 * v;
                }
            }
        }
        __syncthreads();
    }

    // epilogue: combine the two u-streams via LDS, plain stores to tp
    // red[esub][a][reg][lane], a in {0:acc0,1:B,2:C0,3:C1,4:C2}
    if (ust == 1) {
#pragma unroll
        for (int reg = 0; reg < 16; ++reg) {
            red[(((esub * 5 + 0) * 16 + reg) << 6) + lane] = acc0[reg];
            red[(((esub * 5 + 1) * 16 + reg) << 6) + lane] = accB[reg];
            red[(((esub * 5 + 2) * 16 + reg) << 6) + lane] = accC0[reg];
            red[(((esub * 5 + 3) * 16 + reg) << 6) + lane] = accC1[reg];
            red[(((esub * 5 + 4) * 16 + reg) << 6) + lane] = accC2[reg];
        }
    }
    __syncthreads();
    if (ust == 0) {
#pragma unroll
        for (int q = 0; q < 4; ++q) {
#pragma unroll
            for (int rr = 0; rr < 4; ++rr) {
                int reg = q * 4 + rr;
                int el = esub * 32 + q * 8 + half * 4 + rr;
                int e = e0 + el;
                if (e >= E) continue;
                float a0 = acc0[reg] + red[(((esub * 5 + 0) * 16 + reg) << 6) + lane];
                float aB = accB[reg] + red[(((esub * 5 + 1) * 16 + reg) << 6) + lane];
                float c0v = accC0[reg] + red[(((esub * 5 + 2) * 16 + reg) << 6) + lane];
                float c1v = accC1[reg] + red[(((esub * 5 + 3) * 16 + reg) << 6) + lane];
                float c2v = accC2[reg] + red[(((esub * 5 + 4) * 16 + reg) << 6) + lane];
                float4 sv = *(const float4*)&shs[el * 4];
                float* tpe = tp + (size_t)e * 128;
                tpe[col] = PNRM * a0;
                tpe[32 + col * 3 + 0] = PNRM * IS3 * (sv.y * aB + sv.x * c0v);
                tpe[32 + col * 3 + 1] = PNRM * IS3 * (sv.z * aB + sv.x * c1v);
                tpe[32 + col * 3 + 2] = PNRM * IS3 * (sv.w * aB + sv.x * c2v);
            }
        }
    }
}

// ---- K_scan: exclusive prefix sum of deg -> rowptr (1 WG) ----
__global__ __launch_bounds__(1024) void k_scan(const int* __restrict__ deg,
                                               int* __restrict__ rowptr, int N) {
    __shared__ int part[1024];
    const int tid = threadIdx.x;
    const int chunk = (N + 1023) / 1024;
    const int base = tid * chunk;
    int s = 0;
    for (int i = 0; i < chunk; ++i) {
        int n = base + i;
        if (n < N) s += deg[n];
    }
    part[tid] = s;
    __syncthreads();
    for (int off = 1; off < 1024; off <<= 1) {
        int t = 0;
        if (tid >= off) t = part[tid - off];
        __syncthreads();
        if (tid >= off) part[tid] += t;
        __syncthreads();
    }
    int prefix = (tid == 0) ? 0 : part[tid - 1];
    for (int i = 0; i < chunk; ++i) {
        int n = base + i;
        if (n < N) { rowptr[n] = prefix; prefix += deg[n]; }
    }
    if (tid == 0) rowptr[N] = part[1023];
}

// ---- K_fill: bucket edge ids by src ----
__global__ __launch_bounds__(256) void k_fill(const int* __restrict__ ei,
                                              const int* __restrict__ rowptr,
                                              int* __restrict__ cursor,
                                              int* __restrict__ elist, int E) {
    int e = blockIdx.x * 256 + threadIdx.x;
    if (e >= E) return;
    int s = ei[e];
    int pos = rowptr[s] + atomicAdd(&cursor[s], 1);
    elist[pos] = e;
}

// ---- K4: per-node gather-mean + residual + BN stats (no feature atomics) ----
__global__ __launch_bounds__(256) void k4_gather(const float* __restrict__ tp,
                                                 const int* __restrict__ rowptr,
                                                 const int* __restrict__ elist,
                                                 const float* __restrict__ na,
                                                 float* __restrict__ pre,
                                                 float* __restrict__ stats, int N) {
    __shared__ float bns[96];
    const int tid = threadIdx.x;
    if (tid < 96) bns[tid] = 0.f;
    __syncthreads();
    const int o = tid & 127, hf = tid >> 7;
    for (int n = blockIdx.x * 2 + hf; n < N; n += gridDim.x * 2) {
        int r0 = rowptr[n], r1 = rowptr[n + 1];
        float s = 0.f;
        for (int j = r0; j < r1; ++j)
            s += tp[(size_t)elist[j] * 128 + o];
        int dg = r1 - r0;
        float cf = (float)(dg > 0 ? dg : 1);
        float v = s / cf + na[(size_t)n * 128 + o];
        pre[(size_t)n * 128 + o] = v;
        if (o < 32) {
            atomicAdd(&bns[o], v);
            atomicAdd(&bns[32 + o], v * v);
        } else {
            atomicAdd(&bns[64 + (o - 32) / 3], v * v);
        }
    }
    __syncthreads();
    if (tid < 96) atomicAdd(&stats[tid], bns[tid]);
}

// ---- K5: apply batch norm ----
__global__ __launch_bounds__(256) void k5_bn(const float* __restrict__ pre,
                                             const float* __restrict__ stats,
                                             const float* __restrict__ bnw,
                                             const float* __restrict__ bnb,
                                             float* __restrict__ out, int N) {
    size_t idx = (size_t)blockIdx.x * 256 + threadIdx.x;
    if (idx >= (size_t)N * 128) return;
    int o = (int)(idx & 127);
    float v = pre[idx];
    float invN = 1.f / (float)N;
    if (o < 32) {
        float m   = stats[o] * invN;
        float var = stats[32 + o] * invN - m * m;
        out[idx] = (v - m) * rsqrtf(var + EPSV) * bnw[o] + bnb[o];
    } else {
        int j = (o - 32) / 3;
        float vn = rsqrtf(stats[64 + j] * invN * (1.f / 3.f) + EPSV);
        out[idx] = v * vn * bnw[32 + j];
    }
}

extern "C" void kernel_launch(void* const* d_in, const int* in_sizes, int n_in,
                              void* d_out, int out_size, void* d_ws, size_t ws_size,
                              hipStream_t stream) {
    const float* node_attr  = (const float*)d_in[0];
    const int*   edge_index = (const int*)d_in[1];
    const float* edge_attr  = (const float*)d_in[2];
    const float* edge_sh    = (const float*)d_in[3];
    const float* W1  = (const float*)d_in[4];
    const float* b1  = (const float*)d_in[5];
    const float* W2  = (const float*)d_in[6];
    const float* b2  = (const float*)d_in[7];
    const float* bnw = (const float*)d_in[8];
    const float* bnb = (const float*)d_in[9];

    const int N = in_sizes[0] / 128;
    const int E = in_sizes[1] / 2;

    float* tp     = (float*)d_ws;                 // E*128
    float* pre    = tp + (size_t)E * 128;         // N*128
    float* stats  = pre + (size_t)N * 128;        // 96
    int*   deg    = (int*)(stats + 96);           // N
    int*   cursor = deg + N;                      // N
    int*   rowptr = cursor + N;                   // N+1
    int*   elist  = rowptr + N + 1;               // E
    char* pbase = (char*)(elist + E);
    pbase += (16 - ((size_t)pbase & 15)) & 15;    // align 16
    unsigned short* h   = (unsigned short*)pbase;          // E*128 bf16
    unsigned short* W2T = h + (size_t)E * 128;             // 524288
    unsigned short* W1T = W2T + (size_t)524288;            // 16384

    // zero stats + deg + cursor (contiguous)
    hipMemsetAsync(stats, 0, (96 + 2 * (size_t)N) * sizeof(int), stream);

    k0_sw<<<(128 * 4096 + 255) / 256, 256, 0, stream>>>(W2, W2T, 128 * 4096, 12, 4095);
    k0_sw<<<(128 * 128 + 255) / 256, 256, 0, stream>>>(W1, W1T, 128 * 128, 7, 127);
    k1_fc<<<(E + 127) / 128, 256, 0, stream>>>(edge_attr, W1T, b1, edge_index, h, deg, E);
    k_scan<<<1, 1024, 0, stream>>>(deg, rowptr, N);
    k_fill<<<(E + 255) / 256, 256, 0, stream>>>(edge_index, rowptr, cursor, elist, E);
    k2_mfma<<<(E + 63) / 64, 256, 0, stream>>>(h, W2T, b2, node_attr, edge_index,
                                               edge_sh, tp, E);
    k4_gather<<<256, 256, 0, stream>>>(tp, rowptr, elist, node_attr, pre, stats, N);
    size_t ntot = (size_t)N * 128;
    k5_bn<<<(int)((ntot + 255) / 256), 256, 0, stream>>>(pre, stats, bnw, bnb,
                                                         (float*)d_out, N);
}

// Round 5
// 302.894 us; speedup vs baseline: 12.1640x; 1.0479x over previous
//
#include <hip/hip_runtime.h>
#include <math.h>

#define EPSV 1e-5f
#define IS3  0.57735026918962576f   // 1/sqrt(3)
#define PNRM 0.125f                 // 1/sqrt(2*32)

typedef __attribute__((ext_vector_type(8)))  short  short8;
typedef __attribute__((ext_vector_type(16))) float  floatx16;

static __device__ inline unsigned short f2bf(float f) {
    unsigned int u = __float_as_uint(f);
    return (unsigned short)((u + 0x7fff + ((u >> 16) & 1)) >> 16);  // RNE
}
static __device__ inline float bflo(unsigned int u) { return __uint_as_float(u << 16); }
static __device__ inline float bfhi(unsigned int u) { return __uint_as_float(u & 0xffff0000u); }

// async global->LDS, 16B per lane; lds dest = uniform base + lane*16 (HW adds it)
#define GLD16(gp, lp) __builtin_amdgcn_global_load_lds( \
    (const __attribute__((address_space(1))) unsigned int*)(gp), \
    (__attribute__((address_space(3))) unsigned int*)(lp), 16, 0, 0)

// ---- K0: f32 [128 x NC] -> bf16 swizzled col-tiles (write-coalesced).
// dst addr(short) = tile*4096 + (k>>3)*256 + (col&31)*8 + (k&7), tile=col/32
__global__ __launch_bounds__(256) void k0_sw(const float* __restrict__ src,
                                             unsigned short* __restrict__ dst,
                                             int total, int nc) {
    int i = blockIdx.x * 256 + threadIdx.x;
    if (i >= total) return;
    int tile = i >> 12, t = i & 4095;
    int k = ((t >> 8) << 3) | (t & 7);
    int c = (tile << 5) | ((t >> 3) & 31);
    dst[i] = f2bf(src[(size_t)k * nc + c]);
}

// ---- K1: h = relu(ea @ W1 + b1) via MFMA 32x32x16; LDS-bounce epilogue ----
__global__ __launch_bounds__(256) void k1_fc(const float* __restrict__ ea,
                                             const unsigned short* __restrict__ W1T,
                                             const float* __restrict__ b1,
                                             const int* __restrict__ ei,
                                             unsigned short* __restrict__ h,
                                             int* __restrict__ deg, int E) {
    __shared__ __align__(16) unsigned short W1s[16384];   // 32 KB swizzled tiles
    __shared__ __align__(16) unsigned short outT[5120];   // 128 rows x 40 stride
    const int tid = threadIdx.x, lane = tid & 63, wv = tid >> 6;
    const int half = lane >> 5, col = lane & 31;
    const int e0 = blockIdx.x * 128;

    if (tid < 128) { int e = e0 + tid; if (e < E) atomicAdd(&deg[ei[e]], 1); }

#pragma unroll
    for (int q = 0; q < 8; ++q) {
        int chunk = wv * 8 + q;
        GLD16((const char*)W1T + chunk * 1024 + lane * 16, (char*)W1s + chunk * 1024);
    }

    int e = e0 + wv * 32 + col; if (e >= E) e = E - 1;
    short8 afr[8];
#pragma unroll
    for (int c = 0; c < 8; ++c) {
        const float4* p = (const float4*)(ea + (size_t)e * 128 + c * 16 + half * 8);
        float4 f0 = p[0], f1 = p[1];
        short8 v;
        v[0] = (short)f2bf(f0.x); v[1] = (short)f2bf(f0.y);
        v[2] = (short)f2bf(f0.z); v[3] = (short)f2bf(f0.w);
        v[4] = (short)f2bf(f1.x); v[5] = (short)f2bf(f1.y);
        v[6] = (short)f2bf(f1.z); v[7] = (short)f2bf(f1.w);
        afr[c] = v;
    }
    __syncthreads();

#pragma unroll
    for (int jt = 0; jt < 4; ++jt) {
        floatx16 d = {0,0,0,0,0,0,0,0,0,0,0,0,0,0,0,0};
#pragma unroll
        for (int c = 0; c < 8; ++c) {
            short8 bf = *(const short8*)((const char*)W1s + jt * 8192 + (2 * c + half) * 512 + col * 16);
            d = __builtin_amdgcn_mfma_f32_32x32x16_bf16(afr[c], bf, d, 0, 0, 0);
        }
        float b1v = b1[jt * 32 + col];
#pragma unroll
        for (int reg = 0; reg < 16; ++reg) {
            int r = (reg & 3) + 8 * (reg >> 2) + 4 * half;
            float v = d[reg] + b1v;
            v = v > 0.f ? v : 0.f;
            outT[(wv * 32 + r) * 40 + col] = f2bf(v);
        }
        __syncthreads();
#pragma unroll
        for (int ps = 0; ps < 2; ++ps) {
            int lin = ps * 256 + tid;
            int row = lin >> 2, c8 = (lin & 3) * 8;
            int er = e0 + row;
            if (er < E) {
                short8 v = *(const short8*)&outT[row * 40 + c8];
                *(short8*)(h + (size_t)er * 128 + jt * 32 + c8) = v;
            }
        }
        __syncthreads();
    }
}

// ---- K2: MFMA 32x32x16 GEMM (h @ W2) fused with TP; barrier-free K-loop,
//      B fragments streamed global->VGPR (double-buffered), plain stores ----
__global__ __launch_bounds__(256, 2) void k2_mfma(const unsigned short* __restrict__ h,
                                                  const unsigned short* __restrict__ W2T,
                                                  const float* __restrict__ b2,
                                                  const float* __restrict__ na,
                                                  const int* __restrict__ ei,
                                                  const float* __restrict__ sh,
                                                  float* __restrict__ tp, int E) {
    __shared__ __align__(16) char smem[42240];
    unsigned short* As  = (unsigned short*)smem;              // 16384 B
    unsigned short* Ctb = (unsigned short*)(smem + 16384);    // 24576 B
    float* shs = (float*)(smem + 40960);                      // 1024 B
    float* red = (float*)smem;                                // epilogue alias 40960 B

    const int tid = threadIdx.x, lane = tid & 63, wv = tid >> 6;
    const int half = lane >> 5, col = lane & 31;
    const int ust = wv >> 1, esub = wv & 1;
    const int e0 = blockIdx.x * 64;

    if (tid < 64) {
        int e = e0 + tid; int ec = e < E ? e : E - 1;
        float4 s = *(const float4*)(sh + (size_t)ec * 4);
        *(float4*)&shs[tid * 4] = s;
    }

    // coefficient tables (bf16), layout [u][el]
    for (int idx = tid; idx < 2048; idx += 256) {
        int el = idx & 63, u = idx >> 6;
        int e = e0 + el; int ec = e < E ? e : E - 1;
        int dn = ei[E + ec];
        const float* nar = na + (size_t)dn * 128;
        float x0  = nar[u];
        float x10 = nar[32 + u * 3], x11 = nar[33 + u * 3], x12 = nar[34 + u * 3];
        const float* shr = sh + (size_t)ec * 4;
        float s0 = shr[0], s1 = shr[1], s2 = shr[2], s3 = shr[3];
        int o = u * 64 + el;
        Ctb[0 * 2048 + o] = f2bf(x0 * s0);
        Ctb[1 * 2048 + o] = f2bf(x0);
        Ctb[2 * 2048 + o] = f2bf(x10);
        Ctb[3 * 2048 + o] = f2bf(x11);
        Ctb[4 * 2048 + o] = f2bf(x12);
        Ctb[5 * 2048 + o] = f2bf(IS3 * (x10 * s1 + x11 * s2 + x12 * s3));
    }

    // stage A (h-tile, swizzled into frag order), 16 KB
#pragma unroll
    for (int q = 0; q < 4; ++q) {
        int t = wv * 4 + q;
        int g = t >> 3;
        int jj = (t & 7) * 64 + lane;
        int e = e0 + g * 32 + (jj & 31); int ec = e < E ? e : E - 1;
        GLD16((const char*)h + (size_t)ec * 256 + (jj >> 5) * 16,
              (char*)As + g * 8192 + (t & 7) * 1024);
    }
    __syncthreads();

    short8 afr[8];
#pragma unroll
    for (int c = 0; c < 8; ++c)
        afr[c] = *(const short8*)((const char*)As + esub * 8192 + (2 * c + half) * 512 + col * 16);

    float acc0[16] = {}, accB[16] = {}, accC0[16] = {}, accC1[16] = {}, accC2[16] = {};
    const int elb0 = esub * 32 + half * 4;
    const unsigned short* bbase = W2T + half * 256 + col * 8;

#define LOADB(p, br, b2r) do {                                         \
        int _ct = 2 * (p) + ust;                                       \
        const unsigned short* _bp = bbase + (size_t)_ct * 4096;        \
        _Pragma("unroll")                                              \
        for (int _c = 0; _c < 8; ++_c)                                 \
            (br)[_c] = *(const short8*)(_bp + _c * 512);               \
        (b2r) = b2[_ct * 32 + col];                                    \
    } while (0)

#define COMPUTE(p, br, b2v) do {                                                              \
        const int _ct = 2 * (p) + ust;                                                        \
        const int _b = _ct >> 5, _u = _ct & 31;                                               \
        floatx16 d = {0,0,0,0,0,0,0,0,0,0,0,0,0,0,0,0};                                       \
        _Pragma("unroll")                                                                     \
        for (int _c = 0; _c < 8; ++_c)                                                        \
            d = __builtin_amdgcn_mfma_f32_32x32x16_bf16(afr[_c], (br)[_c], d, 0, 0, 0);       \
        if (_b == 0 || _b == 3) {                                                             \
            const unsigned short* tb = Ctb + (_b == 0 ? 0 : 5) * 2048;                        \
            _Pragma("unroll")                                                                 \
            for (int q = 0; q < 4; ++q) {                                                     \
                uint2 cv = *(const uint2*)&tb[_u * 64 + elb0 + q * 8];                        \
                acc0[q * 4 + 0] += bflo(cv.x) * (d[q * 4 + 0] + (b2v));                       \
                acc0[q * 4 + 1] += bfhi(cv.x) * (d[q * 4 + 1] + (b2v));                       \
                acc0[q * 4 + 2] += bflo(cv.y) * (d[q * 4 + 2] + (b2v));                       \
                acc0[q * 4 + 3] += bfhi(cv.y) * (d[q * 4 + 3] + (b2v));                       \
            }                                                                                 \
        } else if (_b == 1) {                                                                 \
            _Pragma("unroll")                                                                 \
            for (int q = 0; q < 4; ++q) {                                                     \
                uint2 cv = *(const uint2*)&Ctb[1 * 2048 + _u * 64 + elb0 + q * 8];            \
                accB[q * 4 + 0] += bflo(cv.x) * (d[q * 4 + 0] + (b2v));                       \
                accB[q * 4 + 1] += bfhi(cv.x) * (d[q * 4 + 1] + (b2v));                       \
                accB[q * 4 + 2] += bflo(cv.y) * (d[q * 4 + 2] + (b2v));                       \
                accB[q * 4 + 3] += bfhi(cv.y) * (d[q * 4 + 3] + (b2v));                       \
            }                                                                                 \
        } else {                                                                              \
            _Pragma("unroll")                                                                 \
            for (int q = 0; q < 4; ++q) {                                                     \
                uint2 cu0 = *(const uint2*)&Ctb[2 * 2048 + _u * 64 + elb0 + q * 8];           \
                uint2 cu1 = *(const uint2*)&Ctb[3 * 2048 + _u * 64 + elb0 + q * 8];           \
                uint2 cu2 = *(const uint2*)&Ctb[4 * 2048 + _u * 64 + elb0 + q * 8];           \
                float f0[4] = {bflo(cu0.x), bfhi(cu0.x), bflo(cu0.y), bfhi(cu0.y)};           \
                float f1[4] = {bflo(cu1.x), bfhi(cu1.x), bflo(cu1.y), bfhi(cu1.y)};           \
                float f2[4] = {bflo(cu2.x), bfhi(cu2.x), bflo(cu2.y), bfhi(cu2.y)};           \
                _Pragma("unroll")                                                             \
                for (int rr = 0; rr < 4; ++rr) {                                              \
                    float v = d[q * 4 + rr] + (b2v);                                          \
                    accC0[q * 4 + rr] += f0[rr] * v;                                          \
                    accC1[q * 4 + rr] += f1[rr] * v;                                          \
                    accC2[q * 4 + rr] += f2[rr] * v;                                          \
                }                                                                             \
            }                                                                                 \
        }                                                                                     \
    } while (0)

    short8 bA[8], bB[8];
    float b2A, b2B;
    LOADB(0, bA, b2A);
    for (int p = 0; p < 64; p += 2) {
        LOADB(p + 1, bB, b2B);
        COMPUTE(p, bA, b2A);
        if (p + 2 < 64) LOADB(p + 2, bA, b2A);
        COMPUTE(p + 1, bB, b2B);
    }

    // epilogue: combine the two u-streams via LDS (red aliases As+Ctb)
    __syncthreads();
    if (ust == 1) {
#pragma unroll
        for (int reg = 0; reg < 16; ++reg) {
            red[(((esub * 5 + 0) * 16 + reg) << 6) + lane] = acc0[reg];
            red[(((esub * 5 + 1) * 16 + reg) << 6) + lane] = accB[reg];
            red[(((esub * 5 + 2) * 16 + reg) << 6) + lane] = accC0[reg];
            red[(((esub * 5 + 3) * 16 + reg) << 6) + lane] = accC1[reg];
            red[(((esub * 5 + 4) * 16 + reg) << 6) + lane] = accC2[reg];
        }
    }
    __syncthreads();
    if (ust == 0) {
#pragma unroll
        for (int q = 0; q < 4; ++q) {
#pragma unroll
            for (int rr = 0; rr < 4; ++rr) {
                int reg = q * 4 + rr;
                int el = esub * 32 + q * 8 + half * 4 + rr;
                int e = e0 + el;
                if (e >= E) continue;
                float a0  = acc0[reg]  + red[(((esub * 5 + 0) * 16 + reg) << 6) + lane];
                float aB  = accB[reg]  + red[(((esub * 5 + 1) * 16 + reg) << 6) + lane];
                float c0v = accC0[reg] + red[(((esub * 5 + 2) * 16 + reg) << 6) + lane];
                float c1v = accC1[reg] + red[(((esub * 5 + 3) * 16 + reg) << 6) + lane];
                float c2v = accC2[reg] + red[(((esub * 5 + 4) * 16 + reg) << 6) + lane];
                float4 sv = *(const float4*)&shs[el * 4];
                float* tpe = tp + (size_t)e * 128;
                tpe[col] = PNRM * a0;
                tpe[32 + col * 3 + 0] = PNRM * IS3 * (sv.y * aB + sv.x * c0v);
                tpe[32 + col * 3 + 1] = PNRM * IS3 * (sv.z * aB + sv.x * c1v);
                tpe[32 + col * 3 + 2] = PNRM * IS3 * (sv.w * aB + sv.x * c2v);
            }
        }
    }
#undef LOADB
#undef COMPUTE
}

// ---- K_scan: exclusive prefix sum of deg -> rowptr (1 WG) ----
__global__ __launch_bounds__(1024) void k_scan(const int* __restrict__ deg,
                                               int* __restrict__ rowptr, int N) {
    __shared__ int part[1024];
    const int tid = threadIdx.x;
    const int chunk = (N + 1023) / 1024;
    const int base = tid * chunk;
    int s = 0;
    for (int i = 0; i < chunk; ++i) {
        int n = base + i;
        if (n < N) s += deg[n];
    }
    part[tid] = s;
    __syncthreads();
    for (int off = 1; off < 1024; off <<= 1) {
        int t = 0;
        if (tid >= off) t = part[tid - off];
        __syncthreads();
        if (tid >= off) part[tid] += t;
        __syncthreads();
    }
    int prefix = (tid == 0) ? 0 : part[tid - 1];
    for (int i = 0; i < chunk; ++i) {
        int n = base + i;
        if (n < N) { rowptr[n] = prefix; prefix += deg[n]; }
    }
    if (tid == 0) rowptr[N] = part[1023];
}

// ---- K_fill: bucket edge ids by src ----
__global__ __launch_bounds__(256) void k_fill(const int* __restrict__ ei,
                                              const int* __restrict__ rowptr,
                                              int* __restrict__ cursor,
                                              int* __restrict__ elist, int E) {
    int e = blockIdx.x * 256 + threadIdx.x;
    if (e >= E) return;
    int s = ei[e];
    int pos = rowptr[s] + atomicAdd(&cursor[s], 1);
    elist[pos] = e;
}

// ---- K4: per-node gather-mean + residual + BN stats ----
__global__ __launch_bounds__(256) void k4_gather(const float* __restrict__ tp,
                                                 const int* __restrict__ rowptr,
                                                 const int* __restrict__ elist,
                                                 const float* __restrict__ na,
                                                 float* __restrict__ pre,
                                                 float* __restrict__ stats, int N) {
    __shared__ float bns[96];
    const int tid = threadIdx.x;
    if (tid < 96) bns[tid] = 0.f;
    __syncthreads();
    const int o = tid & 127, hf = tid >> 7;
    for (int n = blockIdx.x * 2 + hf; n < N; n += gridDim.x * 2) {
        int r0 = rowptr[n], r1 = rowptr[n + 1];
        float s = 0.f;
        for (int j = r0; j < r1; ++j)
            s += tp[(size_t)elist[j] * 128 + o];
        int dg = r1 - r0;
        float cf = (float)(dg > 0 ? dg : 1);
        float v = s / cf + na[(size_t)n * 128 + o];
        pre[(size_t)n * 128 + o] = v;
        if (o < 32) {
            atomicAdd(&bns[o], v);
            atomicAdd(&bns[32 + o], v * v);
        } else {
            atomicAdd(&bns[64 + (o - 32) / 3], v * v);
        }
    }
    __syncthreads();
    if (tid < 96) atomicAdd(&stats[tid], bns[tid]);
}

// ---- K5: apply batch norm ----
__global__ __launch_bounds__(256) void k5_bn(const float* __restrict__ pre,
                                             const float* __restrict__ stats,
                                             const float* __restrict__ bnw,
                                             const float* __restrict__ bnb,
                                             float* __restrict__ out, int N) {
    size_t idx = (size_t)blockIdx.x * 256 + threadIdx.x;
    if (idx >= (size_t)N * 128) return;
    int o = (int)(idx & 127);
    float v = pre[idx];
    float invN = 1.f / (float)N;
    if (o < 32) {
        float m   = stats[o] * invN;
        float var = stats[32 + o] * invN - m * m;
        out[idx] = (v - m) * rsqrtf(var + EPSV) * bnw[o] + bnb[o];
    } else {
        int j = (o - 32) / 3;
        float vn = rsqrtf(stats[64 + j] * invN * (1.f / 3.f) + EPSV);
        out[idx] = v * vn * bnw[32 + j];
    }
}

extern "C" void kernel_launch(void* const* d_in, const int* in_sizes, int n_in,
                              void* d_out, int out_size, void* d_ws, size_t ws_size,
                              hipStream_t stream) {
    const float* node_attr  = (const float*)d_in[0];
    const int*   edge_index = (const int*)d_in[1];
    const float* edge_attr  = (const float*)d_in[2];
    const float* edge_sh    = (const float*)d_in[3];
    const float* W1  = (const float*)d_in[4];
    const float* b1  = (const float*)d_in[5];
    const float* W2  = (const float*)d_in[6];
    const float* b2  = (const float*)d_in[7];
    const float* bnw = (const float*)d_in[8];
    const float* bnb = (const float*)d_in[9];

    const int N = in_sizes[0] / 128;
    const int E = in_sizes[1] / 2;

    float* tp     = (float*)d_ws;                 // E*128
    float* pre    = tp + (size_t)E * 128;         // N*128
    float* stats  = pre + (size_t)N * 128;        // 96
    int*   deg    = (int*)(stats + 96);           // N
    int*   cursor = deg + N;                      // N
    int*   rowptr = cursor + N;                   // N+1
    int*   elist  = rowptr + N + 1;               // E
    char* pbase = (char*)(elist + E);
    pbase += (16 - ((size_t)pbase & 15)) & 15;    // align 16
    unsigned short* h   = (unsigned short*)pbase;          // E*128 bf16
    unsigned short* W2T = h + (size_t)E * 128;             // 524288
    unsigned short* W1T = W2T + (size_t)524288;            // 16384

    hipMemsetAsync(stats, 0, (96 + 2 * (size_t)N) * sizeof(int), stream);

    k0_sw<<<(128 * 4096 + 255) / 256, 256, 0, stream>>>(W2, W2T, 128 * 4096, 4096);
    k0_sw<<<(128 * 128 + 255) / 256, 256, 0, stream>>>(W1, W1T, 128 * 128, 128);
    k1_fc<<<(E + 127) / 128, 256, 0, stream>>>(edge_attr, W1T, b1, edge_index, h, deg, E);
    k_scan<<<1, 1024, 0, stream>>>(deg, rowptr, N);
    k_fill<<<(E + 255) / 256, 256, 0, stream>>>(edge_index, rowptr, cursor, elist, E);
    k2_mfma<<<(E + 63) / 64, 256, 0, stream>>>(h, W2T, b2, node_attr, edge_index,
                                               edge_sh, tp, E);
    k4_gather<<<256, 256, 0, stream>>>(tp, rowptr, elist, node_attr, pre, stats, N);
    size_t ntot = (size_t)N * 128;
    k5_bn<<<(int)((ntot + 255) / 256), 256, 0, stream>>>(pre, stats, bnw, bnb,
                                                         (float*)d_out, N);
}

// Round 7
// 300.729 us; speedup vs baseline: 12.2516x; 1.0072x over previous
//
#include <hip/hip_runtime.h>
#include <math.h>

#define EPSV 1e-5f
#define IS3  0.57735026918962576f   // 1/sqrt(3)
#define PNRM 0.125f                 // 1/sqrt(2*32)

typedef __attribute__((ext_vector_type(8)))  short  short8;
typedef __attribute__((ext_vector_type(16))) float  floatx16;

static __device__ inline unsigned short f2bf(float f) {
    unsigned int u = __float_as_uint(f);
    return (unsigned short)((u + 0x7fff + ((u >> 16) & 1)) >> 16);  // RNE
}
static __device__ inline float bflo(unsigned int u) { return __uint_as_float(u << 16); }
static __device__ inline float bfhi(unsigned int u) { return __uint_as_float(u & 0xffff0000u); }

// async global->LDS, 16B per lane; lds dest = uniform base + lane*16 (HW adds it)
#define GLD16(gp, lp) __builtin_amdgcn_global_load_lds( \
    (const __attribute__((address_space(1))) unsigned int*)(gp), \
    (__attribute__((address_space(3))) unsigned int*)(lp), 16, 0, 0)

// ---- K0: W2 and W1 f32 -> bf16 swizzled col-tiles (write-coalesced, merged).
// tile swizzle (shorts): tile*4096 + (k>>3)*256 + (col&31)*8 + (k&7)
__global__ __launch_bounds__(256) void k0_sw(const float* __restrict__ W2,
                                             const float* __restrict__ W1,
                                             unsigned short* __restrict__ W2T,
                                             unsigned short* __restrict__ W1T) {
    int i = blockIdx.x * 256 + threadIdx.x;
    if (i < 524288) {
        int tile = i >> 12, t = i & 4095;
        int k = ((t >> 8) << 3) | (t & 7);
        int c = (tile << 5) | ((t >> 3) & 31);
        W2T[i] = f2bf(W2[(size_t)k * 4096 + c]);
    } else if (i < 540672) {
        int j = i - 524288;
        int tile = j >> 12, t = j & 4095;
        int k = ((t >> 8) << 3) | (t & 7);
        int c = (tile << 5) | ((t >> 3) & 31);
        W1T[j] = f2bf(W1[(size_t)k * 128 + c]);
    }
}

// ---- K1: h = relu(ea @ W1 + b1) via MFMA 32x32x16.
// Writes h in the A-fragment-swizzled group layout k2 reads directly:
// group g = e/32: short addr = g*4096 + (k>>3)*256 + (e&31)*8 + (k&7).
// Per-jt per-wave padded-LDS bounce (stride 264), no cross-wave barriers.
__global__ __launch_bounds__(256) void k1_fc(const float* __restrict__ ea,
                                             const unsigned short* __restrict__ W1T,
                                             const float* __restrict__ b1,
                                             const int* __restrict__ ei,
                                             unsigned short* __restrict__ hsw,
                                             int* __restrict__ deg, int E) {
    __shared__ __align__(16) unsigned short W1s[16384];     // 32 KB swizzled tiles
    __shared__ __align__(16) unsigned short bounce[4 * 1056];  // 8.4 KB
    const int tid = threadIdx.x, lane = tid & 63, wv = tid >> 6;
    const int half = lane >> 5, col = lane & 31;
    const int e0 = blockIdx.x * 128;

    if (tid < 128) { int e = e0 + tid; if (e < E) atomicAdd(&deg[ei[e]], 1); }

#pragma unroll
    for (int q = 0; q < 8; ++q) {
        int chunk = wv * 8 + q;
        GLD16((const char*)W1T + chunk * 1024 + lane * 16, (char*)W1s + chunk * 1024);
    }

    int e = e0 + wv * 32 + col; if (e >= E) e = E - 1;
    short8 afr[8];
#pragma unroll
    for (int c = 0; c < 8; ++c) {
        const float4* p = (const float4*)(ea + (size_t)e * 128 + c * 16 + half * 8);
        float4 f0 = p[0], f1 = p[1];
        short8 v;
        v[0] = (short)f2bf(f0.x); v[1] = (short)f2bf(f0.y);
        v[2] = (short)f2bf(f0.z); v[3] = (short)f2bf(f0.w);
        v[4] = (short)f2bf(f1.x); v[5] = (short)f2bf(f1.y);
        v[6] = (short)f2bf(f1.z); v[7] = (short)f2bf(f1.w);
        afr[c] = v;
    }
    __syncthreads();

    unsigned short* myb = bounce + wv * 1056;   // 4 chunks x 264 shorts
    const int gg = blockIdx.x * 4 + wv;
#pragma unroll
    for (int jt = 0; jt < 4; ++jt) {
        floatx16 d = {0,0,0,0,0,0,0,0,0,0,0,0,0,0,0,0};
#pragma unroll
        for (int c = 0; c < 8; ++c) {
            short8 bf = *(const short8*)((const char*)W1s + jt * 8192 + (2 * c + half) * 512 + col * 16);
            d = __builtin_amdgcn_mfma_f32_32x32x16_bf16(afr[c], bf, d, 0, 0, 0);
        }
        float b1v = b1[jt * 32 + col];
        // scatter MFMA regs into bounce: [chunk=col>>3][r][k7=col&7]
#pragma unroll
        for (int reg = 0; reg < 16; ++reg) {
            int r = (reg & 3) + 8 * (reg >> 2) + 4 * half;
            float v = d[reg] + b1v;
            v = v > 0.f ? v : 0.f;
            myb[(col >> 3) * 264 + r * 8 + (col & 7)] = f2bf(v);
        }
        // coalesced readback: lane reads 2 short8s, stores 1KB-contiguous
#pragma unroll
        for (int s = 0; s < 2; ++s) {
            short8 v = *(const short8*)&myb[(s * 2 + (lane >> 5)) * 264 + (lane & 31) * 8];
            *(short8*)(hsw + (size_t)gg * 4096 + jt * 1024 + s * 512 + lane * 8) = v;
        }
    }
}

// ---- K2: MFMA 32x32x16 GEMM (h @ W2) fused with TP contraction.
// 3-buffer LDS B-staging via global_load_lds, one raw s_barrier per tile,
// manual s_waitcnt vmcnt(5) (never drain). A frags direct from swizzled h.
__global__ __launch_bounds__(256, 2) void k2_mfma(const unsigned short* __restrict__ hsw,
                                                  const unsigned short* __restrict__ W2T,
                                                  const float* __restrict__ b2,
                                                  const float* __restrict__ na,
                                                  const int* __restrict__ ei,
                                                  const float* __restrict__ sh,
                                                  float* __restrict__ tp, int E) {
    __shared__ __align__(16) char smem[73728];
    // [0,49152): 3 x 16 KB B buffers; [49152,73728): coef tables (6 x 2048 bf16)
    unsigned short* Ctb = (unsigned short*)(smem + 49152);
    float* red = (float*)smem;   // 32 KB epilogue alias

    const int tid = threadIdx.x, lane = tid & 63, wv = tid >> 6;
    const int half = lane >> 5, col = lane & 31;
    const int ust = wv >> 1, esub = wv & 1;
    const int e0 = blockIdx.x * 64;

    // coef tables (bf16), [u][el], pre-scaled by PNRM / PNRM*IS3 / s0
    for (int idx = tid; idx < 2048; idx += 256) {
        int el = idx & 63, u = idx >> 6;
        int e = e0 + el; int ec = e < E ? e : E - 1;
        int dn = ei[E + ec];
        const float* nar = na + (size_t)dn * 128;
        float x0  = nar[u];
        float x10 = nar[32 + u * 3], x11 = nar[33 + u * 3], x12 = nar[34 + u * 3];
        const float* shr = sh + (size_t)ec * 4;
        float s0 = shr[0], s1 = shr[1], s2 = shr[2], s3 = shr[3];
        int o = u * 64 + el;
        Ctb[0 * 2048 + o] = f2bf(PNRM * x0 * s0);
        Ctb[1 * 2048 + o] = f2bf(PNRM * IS3 * x0);
        Ctb[2 * 2048 + o] = f2bf(PNRM * IS3 * s0 * x10);
        Ctb[3 * 2048 + o] = f2bf(PNRM * IS3 * s0 * x11);
        Ctb[4 * 2048 + o] = f2bf(PNRM * IS3 * s0 * x12);
        Ctb[5 * 2048 + o] = f2bf(PNRM * IS3 * (x10 * s1 + x11 * s2 + x12 * s3));
    }

    // A fragments direct from swizzled h (coalesced 512B/half-wave)
    const int gg = blockIdx.x * 2 + esub;
    short8 afr[8];
#pragma unroll
    for (int c = 0; c < 8; ++c)
        afr[c] = *(const short8*)(hsw + (size_t)gg * 4096 + (2 * c + half) * 256 + col * 8);

    __syncthreads();   // Ctb visible; drains all prior vmem (count starts clean)

    // prologue: stage p=0,1 (each section = 4 GLD16 + 1 b2 load = 5 vmem ops)
    int offA = 0, offB = 16384, offC = 32768;
#pragma unroll
    for (int q = 0; q < 4; ++q) {
        int chunk = wv * 4 + q;
        GLD16((const char*)W2T + chunk * 1024 + lane * 16, smem + offA + chunk * 1024);
    }
    float b2cur = b2[ust * 32 + col];
    asm volatile("" ::: "memory");
#pragma unroll
    for (int q = 0; q < 4; ++q) {
        int chunk = wv * 4 + q;
        GLD16((const char*)W2T + 16384 + chunk * 1024 + lane * 16, smem + offB + chunk * 1024);
    }
    float b2nxt = b2[(2 + ust) * 32 + col];
    asm volatile("" ::: "memory");

    float acc0[16] = {}, accB[16] = {}, accC0[16] = {}, accC1[16] = {}, accC2[16] = {};
    const int elb0 = esub * 32 + half * 4;

    for (int p = 0; p < 64; ++p) {
        if (p == 63) asm volatile("s_waitcnt vmcnt(0)" ::: "memory");
        else         asm volatile("s_waitcnt vmcnt(5)" ::: "memory");
        asm volatile("s_barrier" ::: "memory");

        const int ct = 2 * p + ust;
        const int b = ct >> 5, u = ct & 31;
        const char* bb = smem + offA + ust * 8192;

        floatx16 d = {0,0,0,0,0,0,0,0,0,0,0,0,0,0,0,0};
#pragma unroll
        for (int c = 0; c < 8; ++c) {
            short8 bf = *(const short8*)(bb + (2 * c + half) * 512 + col * 16);
            d = __builtin_amdgcn_mfma_f32_32x32x16_bf16(afr[c], bf, d, 0, 0, 0);
        }
        const float b2v = b2cur;

        if (b == 0 || b == 3) {
            const unsigned short* tb = Ctb + (b == 0 ? 0 : 5) * 2048;
#pragma unroll
            for (int q = 0; q < 4; ++q) {
                uint2 cv = *(const uint2*)&tb[u * 64 + elb0 + q * 8];
                acc0[q * 4 + 0] += bflo(cv.x) * (d[q * 4 + 0] + b2v);
                acc0[q * 4 + 1] += bfhi(cv.x) * (d[q * 4 + 1] + b2v);
                acc0[q * 4 + 2] += bflo(cv.y) * (d[q * 4 + 2] + b2v);
                acc0[q * 4 + 3] += bfhi(cv.y) * (d[q * 4 + 3] + b2v);
            }
        } else if (b == 1) {
#pragma unroll
            for (int q = 0; q < 4; ++q) {
                uint2 cv = *(const uint2*)&Ctb[1 * 2048 + u * 64 + elb0 + q * 8];
                accB[q * 4 + 0] += bflo(cv.x) * (d[q * 4 + 0] + b2v);
                accB[q * 4 + 1] += bfhi(cv.x) * (d[q * 4 + 1] + b2v);
                accB[q * 4 + 2] += bflo(cv.y) * (d[q * 4 + 2] + b2v);
                accB[q * 4 + 3] += bfhi(cv.y) * (d[q * 4 + 3] + b2v);
            }
        } else {  // b == 2
#pragma unroll
            for (int q = 0; q < 4; ++q) {
                uint2 cu0 = *(const uint2*)&Ctb[2 * 2048 + u * 64 + elb0 + q * 8];
                uint2 cu1 = *(const uint2*)&Ctb[3 * 2048 + u * 64 + elb0 + q * 8];
                uint2 cu2 = *(const uint2*)&Ctb[4 * 2048 + u * 64 + elb0 + q * 8];
                float f0[4] = {bflo(cu0.x), bfhi(cu0.x), bflo(cu0.y), bfhi(cu0.y)};
                float f1[4] = {bflo(cu1.x), bfhi(cu1.x), bflo(cu1.y), bfhi(cu1.y)};
                float f2[4] = {bflo(cu2.x), bfhi(cu2.x), bflo(cu2.y), bfhi(cu2.y)};
#pragma unroll
                for (int rr = 0; rr < 4; ++rr) {
                    float v = d[q * 4 + rr] + b2v;
                    accC0[q * 4 + rr] += f0[rr] * v;
                    accC1[q * 4 + rr] += f1[rr] * v;
                    accC2[q * 4 + rr] += f2[rr] * v;
                }
            }
        }

        // stage p+2 into bufC + prefetch its b2 (exactly 5 vmem ops/section)
        float b2new = 0.f;
        if (p + 2 < 64) {
#pragma unroll
            for (int q = 0; q < 4; ++q) {
                int chunk = wv * 4 + q;
                GLD16((const char*)W2T + (p + 2) * 16384 + chunk * 1024 + lane * 16,
                      smem + offC + chunk * 1024);
            }
            b2new = b2[(2 * (p + 2) + ust) * 32 + col];
        }
        int t = offA; offA = offB; offB = offC; offC = t;
        b2cur = b2nxt; b2nxt = b2new;
    }

    // epilogue: combine the two u-streams via LDS, plain stores to tp
    __syncthreads();
    if (ust == 1) {
#pragma unroll
        for (int q = 0; q < 4; ++q) {
#pragma unroll
            for (int rr = 0; rr < 4; ++rr) {
                int reg = q * 4 + rr;
                int el = esub * 32 + q * 8 + half * 4 + rr;
                int e = e0 + el; int ec = e < E ? e : E - 1;
                float4 sv = *(const float4*)(sh + (size_t)ec * 4);
                red[(((esub * 4 + 0) * 16 + reg) << 6) + lane] = acc0[reg];
                red[(((esub * 4 + 1) * 16 + reg) << 6) + lane] = sv.y * accB[reg] + accC0[reg];
                red[(((esub * 4 + 2) * 16 + reg) << 6) + lane] = sv.z * accB[reg] + accC1[reg];
                red[(((esub * 4 + 3) * 16 + reg) << 6) + lane] = sv.w * accB[reg] + accC2[reg];
            }
        }
    }
    __syncthreads();
    if (ust == 0) {
#pragma unroll
        for (int q = 0; q < 4; ++q) {
#pragma unroll
            for (int rr = 0; rr < 4; ++rr) {
                int reg = q * 4 + rr;
                int el = esub * 32 + q * 8 + half * 4 + rr;
                int e = e0 + el;
                if (e >= E) continue;
                float4 sv = *(const float4*)(sh + (size_t)e * 4);
                float a0 = acc0[reg] + red[(((esub * 4 + 0) * 16 + reg) << 6) + lane];
                float o0 = sv.y * accB[reg] + accC0[reg] + red[(((esub * 4 + 1) * 16 + reg) << 6) + lane];
                float o1 = sv.z * accB[reg] + accC1[reg] + red[(((esub * 4 + 2) * 16 + reg) << 6) + lane];
                float o2 = sv.w * accB[reg] + accC2[reg] + red[(((esub * 4 + 3) * 16 + reg) << 6) + lane];
                float* tpe = tp + (size_t)e * 128;
                tpe[col] = a0;
                tpe[32 + col * 3 + 0] = o0;
                tpe[32 + col * 3 + 1] = o1;
                tpe[32 + col * 3 + 2] = o2;
            }
        }
    }
}

// ---- K_scan: exclusive prefix sum of deg -> rowptr (1 WG) ----
__global__ __launch_bounds__(1024) void k_scan(const int* __restrict__ deg,
                                               int* __restrict__ rowptr, int N) {
    __shared__ int part[1024];
    const int tid = threadIdx.x;
    const int chunk = (N + 1023) / 1024;
    const int base = tid * chunk;
    int s = 0;
    for (int i = 0; i < chunk; ++i) {
        int n = base + i;
        if (n < N) s += deg[n];
    }
    part[tid] = s;
    __syncthreads();
    for (int off = 1; off < 1024; off <<= 1) {
        int t = 0;
        if (tid >= off) t = part[tid - off];
        __syncthreads();
        if (tid >= off) part[tid] += t;
        __syncthreads();
    }
    int prefix = (tid == 0) ? 0 : part[tid - 1];
    for (int i = 0; i < chunk; ++i) {
        int n = base + i;
        if (n < N) { rowptr[n] = prefix; prefix += deg[n]; }
    }
    if (tid == 0) rowptr[N] = part[1023];
}

// ---- K_fill: bucket edge ids by src ----
__global__ __launch_bounds__(256) void k_fill(const int* __restrict__ ei,
                                              const int* __restrict__ rowptr,
                                              int* __restrict__ cursor,
                                              int* __restrict__ elist, int E) {
    int e = blockIdx.x * 256 + threadIdx.x;
    if (e >= E) return;
    int s = ei[e];
    int pos = rowptr[s] + atomicAdd(&cursor[s], 1);
    elist[pos] = e;
}

// ---- K4: per-node gather-mean + residual + BN stats ----
__global__ __launch_bounds__(256) void k4_gather(const float* __restrict__ tp,
                                                 const int* __restrict__ rowptr,
                                                 const int* __restrict__ elist,
                                                 const float* __restrict__ na,
                                                 float* __restrict__ pre,
                                                 float* __restrict__ stats, int N) {
    __shared__ float bns[96];
    const int tid = threadIdx.x;
    if (tid < 96) bns[tid] = 0.f;
    __syncthreads();
    const int o = tid & 127, hf = tid >> 7;
    for (int n = blockIdx.x * 2 + hf; n < N; n += gridDim.x * 2) {
        int r0 = rowptr[n], r1 = rowptr[n + 1];
        float s = 0.f;
        for (int j = r0; j < r1; ++j)
            s += tp[(size_t)elist[j] * 128 + o];
        int dg = r1 - r0;
        float cf = (float)(dg > 0 ? dg : 1);
        float v = s / cf + na[(size_t)n * 128 + o];
        pre[(size_t)n * 128 + o] = v;
        if (o < 32) {
            atomicAdd(&bns[o], v);
            atomicAdd(&bns[32 + o], v * v);
        } else {
            atomicAdd(&bns[64 + (o - 32) / 3], v * v);
        }
    }
    __syncthreads();
    if (tid < 96) atomicAdd(&stats[tid], bns[tid]);
}

// ---- K5: apply batch norm ----
__global__ __launch_bounds__(256) void k5_bn(const float* __restrict__ pre,
                                             const float* __restrict__ stats,
                                             const float* __restrict__ bnw,
                                             const float* __restrict__ bnb,
                                             float* __restrict__ out, int N) {
    size_t idx = (size_t)blockIdx.x * 256 + threadIdx.x;
    if (idx >= (size_t)N * 128) return;
    int o = (int)(idx & 127);
    float v = pre[idx];
    float invN = 1.f / (float)N;
    if (o < 32) {
        float m   = stats[o] * invN;
        float var = stats[32 + o] * invN - m * m;
        out[idx] = (v - m) * rsqrtf(var + EPSV) * bnw[o] + bnb[o];
    } else {
        int j = (o - 32) / 3;
        float vn = rsqrtf(stats[64 + j] * invN * (1.f / 3.f) + EPSV);
        out[idx] = v * vn * bnw[32 + j];
    }
}

extern "C" void kernel_launch(void* const* d_in, const int* in_sizes, int n_in,
                              void* d_out, int out_size, void* d_ws, size_t ws_size,
                              hipStream_t stream) {
    const float* node_attr  = (const float*)d_in[0];
    const int*   edge_index = (const int*)d_in[1];
    const float* edge_attr  = (const float*)d_in[2];
    const float* edge_sh    = (const float*)d_in[3];
    const float* W1  = (const float*)d_in[4];
    const float* b1  = (const float*)d_in[5];
    const float* W2  = (const float*)d_in[6];
    const float* b2  = (const float*)d_in[7];
    const float* bnw = (const float*)d_in[8];
    const float* bnb = (const float*)d_in[9];

    const int N = in_sizes[0] / 128;
    const int E = in_sizes[1] / 2;
    const int ngroups = ((E + 127) / 128) * 4;

    float* tp     = (float*)d_ws;                 // E*128
    float* pre    = tp + (size_t)E * 128;         // N*128
    float* stats  = pre + (size_t)N * 128;        // 96
    int*   deg    = (int*)(stats + 96);           // N
    int*   cursor = deg + N;                      // N
    int*   rowptr = cursor + N;                   // N+1
    int*   elist  = rowptr + N + 1;               // E
    char* pbase = (char*)(elist + E);
    pbase += (16 - ((size_t)pbase & 15)) & 15;    // align 16
    unsigned short* hsw = (unsigned short*)pbase;          // ngroups*4096 bf16
    unsigned short* W2T = hsw + (size_t)ngroups * 4096;    // 524288
    unsigned short* W1T = W2T + (size_t)524288;            // 16384

    hipMemsetAsync(stats, 0, (96 + 2 * (size_t)N) * sizeof(int), stream);

    k0_sw<<<(540672 + 255) / 256, 256, 0, stream>>>(W2, W1, W2T, W1T);
    k1_fc<<<(E + 127) / 128, 256, 0, stream>>>(edge_attr, W1T, b1, edge_index, hsw, deg, E);
    k_scan<<<1, 1024, 0, stream>>>(deg, rowptr, N);
    k_fill<<<(E + 255) / 256, 256, 0, stream>>>(edge_index, rowptr, cursor, elist, E);
    k2_mfma<<<(E + 63) / 64, 256, 0, stream>>>(hsw, W2T, b2, node_attr, edge_index,
                                               edge_sh, tp, E);
    k4_gather<<<512, 256, 0, stream>>>(tp, rowptr, elist, node_attr, pre, stats, N);
    size_t ntot = (size_t)N * 128;
    k5_bn<<<(int)((ntot + 255) / 256), 256, 0, stream>>>(pre, stats, bnw, bnb,
                                                         (float*)d_out, N);
}

// Round 8
// 259.975 us; speedup vs baseline: 14.1722x; 1.1568x over previous
//
#include <hip/hip_runtime.h>
#include <math.h>

#define EPSV 1e-5f
#define IS3  0.57735026918962576f   // 1/sqrt(3)
#define PNRM 0.125f                 // 1/sqrt(2*32)

typedef __attribute__((ext_vector_type(8)))  short  short8;
typedef __attribute__((ext_vector_type(16))) float  floatx16;

static __device__ inline unsigned short f2bf(float f) {
    unsigned int u = __float_as_uint(f);
    return (unsigned short)((u + 0x7fff + ((u >> 16) & 1)) >> 16);  // RNE
}
static __device__ inline float bflo(unsigned int u) { return __uint_as_float(u << 16); }
static __device__ inline float bfhi(unsigned int u) { return __uint_as_float(u & 0xffff0000u); }

// async global->LDS, 16B per lane; lds dest = uniform base + lane*16 (HW adds it)
#define GLD16(gp, lp) __builtin_amdgcn_global_load_lds( \
    (const __attribute__((address_space(1))) unsigned int*)(gp), \
    (__attribute__((address_space(3))) unsigned int*)(lp), 16, 0, 0)

// ---- K0: coalesced LDS-transpose f32 -> bf16 swizzled col-tiles, + zeroing.
// blocks 0..127: W2 col-tiles; 128..131: W1 col-tiles; 132+: zero ints.
// tile layout (shorts): tile*4096 + kc*256 + (c&31)*8 + k7
__global__ __launch_bounds__(256) void k0_tile(const float* __restrict__ W2,
                                               const float* __restrict__ W1,
                                               unsigned short* __restrict__ W2T,
                                               unsigned short* __restrict__ W1T,
                                               int* __restrict__ zbase, int zn) {
    const int bx = blockIdx.x, tid = threadIdx.x;
    if (bx >= 132) {
        int i = (bx - 132) * 256 + tid;
        if (i < zn) zbase[i] = 0;
        return;
    }
    __shared__ float tile[128 * 33];
    const float* src;
    unsigned short* dst;
    int nc, tb;
    if (bx < 128) { src = W2; dst = W2T; nc = 4096; tb = bx; }
    else          { src = W1; dst = W1T; nc = 128;  tb = bx - 128; }
    const int c0 = tb * 32;
#pragma unroll
    for (int r = 0; r < 16; ++r) {
        int lin = r * 256 + tid;
        int k = lin >> 5, c = lin & 31;
        tile[k * 33 + c] = src[(size_t)k * nc + c0 + c];
    }
    __syncthreads();
#pragma unroll
    for (int r = 0; r < 2; ++r) {
        int g = r * 256 + tid;          // 0..511
        int kc = g >> 5, c = g & 31;
        short8 v;
#pragma unroll
        for (int j = 0; j < 8; ++j)
            v[j] = (short)f2bf(tile[(kc * 8 + j) * 33 + c]);
        *(short8*)(dst + (size_t)tb * 4096 + kc * 256 + c * 8) = v;
    }
}

// ---- K1: h = relu(ea @ W1 + b1) via MFMA 32x32x16.
// Writes h in the A-fragment-swizzled group layout k2 reads directly:
// group g = e/32: short addr = g*4096 + (k>>3)*256 + (e&31)*8 + (k&7).
__global__ __launch_bounds__(256) void k1_fc(const float* __restrict__ ea,
                                             const unsigned short* __restrict__ W1T,
                                             const float* __restrict__ b1,
                                             const int* __restrict__ ei,
                                             unsigned short* __restrict__ hsw,
                                             int* __restrict__ deg, int E) {
    __shared__ __align__(16) unsigned short W1s[16384];     // 32 KB swizzled tiles
    __shared__ __align__(16) unsigned short bounce[4 * 1056];  // 8.4 KB
    const int tid = threadIdx.x, lane = tid & 63, wv = tid >> 6;
    const int half = lane >> 5, col = lane & 31;
    const int e0 = blockIdx.x * 128;

    if (tid < 128) { int e = e0 + tid; if (e < E) atomicAdd(&deg[ei[e]], 1); }

#pragma unroll
    for (int q = 0; q < 8; ++q) {
        int chunk = wv * 8 + q;
        GLD16((const char*)W1T + chunk * 1024 + lane * 16, (char*)W1s + chunk * 1024);
    }

    int e = e0 + wv * 32 + col; if (e >= E) e = E - 1;
    short8 afr[8];
#pragma unroll
    for (int c = 0; c < 8; ++c) {
        const float4* p = (const float4*)(ea + (size_t)e * 128 + c * 16 + half * 8);
        float4 f0 = p[0], f1 = p[1];
        short8 v;
        v[0] = (short)f2bf(f0.x); v[1] = (short)f2bf(f0.y);
        v[2] = (short)f2bf(f0.z); v[3] = (short)f2bf(f0.w);
        v[4] = (short)f2bf(f1.x); v[5] = (short)f2bf(f1.y);
        v[6] = (short)f2bf(f1.z); v[7] = (short)f2bf(f1.w);
        afr[c] = v;
    }
    __syncthreads();

    unsigned short* myb = bounce + wv * 1056;   // 4 chunks x 264 shorts
    const int gg = blockIdx.x * 4 + wv;
#pragma unroll
    for (int jt = 0; jt < 4; ++jt) {
        floatx16 d = {0,0,0,0,0,0,0,0,0,0,0,0,0,0,0,0};
#pragma unroll
        for (int c = 0; c < 8; ++c) {
            short8 bf = *(const short8*)((const char*)W1s + jt * 8192 + (2 * c + half) * 512 + col * 16);
            d = __builtin_amdgcn_mfma_f32_32x32x16_bf16(afr[c], bf, d, 0, 0, 0);
        }
        float b1v = b1[jt * 32 + col];
#pragma unroll
        for (int reg = 0; reg < 16; ++reg) {
            int r = (reg & 3) + 8 * (reg >> 2) + 4 * half;
            float v = d[reg] + b1v;
            v = v > 0.f ? v : 0.f;
            myb[(col >> 3) * 264 + r * 8 + (col & 7)] = f2bf(v);
        }
#pragma unroll
        for (int s = 0; s < 2; ++s) {
            short8 v = *(const short8*)&myb[(s * 2 + (lane >> 5)) * 264 + (lane & 31) * 8];
            *(short8*)(hsw + (size_t)gg * 4096 + jt * 1024 + s * 512 + lane * 8) = v;
        }
    }
}

// ---- K2: MFMA 32x32x16 GEMM (h @ W2) fused with TP contraction.
// Barrier-free K-loop: B fragments streamed global->VGPR, 3-buffer rotation
// (2-section lookahead). Also performs CSR edge-bucketing (merged k_fill).
__global__ __launch_bounds__(256, 2) void k2_mfma(const unsigned short* __restrict__ hsw,
                                                  const unsigned short* __restrict__ W2T,
                                                  const float* __restrict__ b2,
                                                  const float* __restrict__ na,
                                                  const int* __restrict__ ei,
                                                  const float* __restrict__ sh,
                                                  const int* __restrict__ rowptr,
                                                  int* __restrict__ cursor,
                                                  int* __restrict__ elist,
                                                  float* __restrict__ tp, int E) {
    __shared__ __align__(16) char smem[32768];
    unsigned short* Ctb = (unsigned short*)smem;   // 6 x 4 KB coef tables
    float* red = (float*)smem;                     // 32 KB epilogue alias

    const int tid = threadIdx.x, lane = tid & 63, wv = tid >> 6;
    const int half = lane >> 5, col = lane & 31;
    const int ust = wv >> 1, esub = wv & 1;
    const int e0 = blockIdx.x * 64;

    // merged k_fill: bucket this block's edges into the CSR elist
    if (tid < 64) {
        int e = e0 + tid;
        if (e < E) {
            int s = ei[e];
            int pos = rowptr[s] + atomicAdd(&cursor[s], 1);
            elist[pos] = e;
        }
    }

    // coef tables (bf16), [u][el], pre-scaled by PNRM / PNRM*IS3 / s0
    for (int idx = tid; idx < 2048; idx += 256) {
        int el = idx & 63, u = idx >> 6;
        int e = e0 + el; int ec = e < E ? e : E - 1;
        int dn = ei[E + ec];
        const float* nar = na + (size_t)dn * 128;
        float x0  = nar[u];
        float x10 = nar[32 + u * 3], x11 = nar[33 + u * 3], x12 = nar[34 + u * 3];
        const float* shr = sh + (size_t)ec * 4;
        float s0 = shr[0], s1 = shr[1], s2 = shr[2], s3 = shr[3];
        int o = u * 64 + el;
        Ctb[0 * 2048 + o] = f2bf(PNRM * x0 * s0);
        Ctb[1 * 2048 + o] = f2bf(PNRM * IS3 * x0);
        Ctb[2 * 2048 + o] = f2bf(PNRM * IS3 * s0 * x10);
        Ctb[3 * 2048 + o] = f2bf(PNRM * IS3 * s0 * x11);
        Ctb[4 * 2048 + o] = f2bf(PNRM * IS3 * s0 * x12);
        Ctb[5 * 2048 + o] = f2bf(PNRM * IS3 * (x10 * s1 + x11 * s2 + x12 * s3));
    }

    // A fragments direct from swizzled h (coalesced 512B/half-wave)
    const int gg = blockIdx.x * 2 + esub;
    short8 afr[8];
#pragma unroll
    for (int c = 0; c < 8; ++c)
        afr[c] = *(const short8*)(hsw + (size_t)gg * 4096 + (2 * c + half) * 256 + col * 8);

    __syncthreads();

    float acc0[16] = {}, accB[16] = {}, accC0[16] = {}, accC1[16] = {}, accC2[16] = {};
    const int elb0 = esub * 32 + half * 4;
    const unsigned short* bbase = W2T + half * 256 + col * 8;

#define LOADB(p, br, b2r) do {                                         \
        int _ct = 2 * (p) + ust;                                       \
        const unsigned short* _bp = bbase + (size_t)_ct * 4096;        \
        _Pragma("unroll")                                              \
        for (int _c = 0; _c < 8; ++_c)                                 \
            (br)[_c] = *(const short8*)(_bp + _c * 512);               \
        (b2r) = b2[_ct * 32 + col];                                    \
    } while (0)

#define COMPUTE(p, br, b2v) do {                                                              \
        const int _ct = 2 * (p) + ust;                                                        \
        const int _b = _ct >> 5, _u = _ct & 31;                                               \
        floatx16 d = {0,0,0,0,0,0,0,0,0,0,0,0,0,0,0,0};                                       \
        _Pragma("unroll")                                                                     \
        for (int _c = 0; _c < 8; ++_c)                                                        \
            d = __builtin_amdgcn_mfma_f32_32x32x16_bf16(afr[_c], (br)[_c], d, 0, 0, 0);       \
        if (_b == 0 || _b == 3) {                                                             \
            const unsigned short* tb = Ctb + (_b == 0 ? 0 : 5) * 2048;                        \
            _Pragma("unroll")                                                                 \
            for (int q = 0; q < 4; ++q) {                                                     \
                uint2 cv = *(const uint2*)&tb[_u * 64 + elb0 + q * 8];                        \
                acc0[q * 4 + 0] += bflo(cv.x) * (d[q * 4 + 0] + (b2v));                       \
                acc0[q * 4 + 1] += bfhi(cv.x) * (d[q * 4 + 1] + (b2v));                       \
                acc0[q * 4 + 2] += bflo(cv.y) * (d[q * 4 + 2] + (b2v));                       \
                acc0[q * 4 + 3] += bfhi(cv.y) * (d[q * 4 + 3] + (b2v));                       \
            }                                                                                 \
        } else if (_b == 1) {                                                                 \
            _Pragma("unroll")                                                                 \
            for (int q = 0; q < 4; ++q) {                                                     \
                uint2 cv = *(const uint2*)&Ctb[1 * 2048 + _u * 64 + elb0 + q * 8];            \
                accB[q * 4 + 0] += bflo(cv.x) * (d[q * 4 + 0] + (b2v));                       \
                accB[q * 4 + 1] += bfhi(cv.x) * (d[q * 4 + 1] + (b2v));                       \
                accB[q * 4 + 2] += bflo(cv.y) * (d[q * 4 + 2] + (b2v));                       \
                accB[q * 4 + 3] += bfhi(cv.y) * (d[q * 4 + 3] + (b2v));                       \
            }                                                                                 \
        } else {                                                                              \
            _Pragma("unroll")                                                                 \
            for (int q = 0; q < 4; ++q) {                                                     \
                uint2 cu0 = *(const uint2*)&Ctb[2 * 2048 + _u * 64 + elb0 + q * 8];           \
                uint2 cu1 = *(const uint2*)&Ctb[3 * 2048 + _u * 64 + elb0 + q * 8];           \
                uint2 cu2 = *(const uint2*)&Ctb[4 * 2048 + _u * 64 + elb0 + q * 8];           \
                float f0[4] = {bflo(cu0.x), bfhi(cu0.x), bflo(cu0.y), bfhi(cu0.y)};           \
                float f1[4] = {bflo(cu1.x), bfhi(cu1.x), bflo(cu1.y), bfhi(cu1.y)};           \
                float f2[4] = {bflo(cu2.x), bfhi(cu2.x), bflo(cu2.y), bfhi(cu2.y)};           \
                _Pragma("unroll")                                                             \
                for (int rr = 0; rr < 4; ++rr) {                                              \
                    float v = d[q * 4 + rr] + (b2v);                                          \
                    accC0[q * 4 + rr] += f0[rr] * v;                                          \
                    accC1[q * 4 + rr] += f1[rr] * v;                                          \
                    accC2[q * 4 + rr] += f2[rr] * v;                                          \
                }                                                                             \
            }                                                                                 \
        }                                                                                     \
    } while (0)

    short8 bA[8], bB[8], bC[8];
    float b2A, b2B, b2C;
    LOADB(0, bA, b2A); LOADB(1, bB, b2B); LOADB(2, bC, b2C);
    for (int p = 0; p < 60; p += 3) {
        COMPUTE(p,     bA, b2A); LOADB(p + 3, bA, b2A);
        COMPUTE(p + 1, bB, b2B); LOADB(p + 4, bB, b2B);
        COMPUTE(p + 2, bC, b2C); LOADB(p + 5, bC, b2C);
    }
    COMPUTE(60, bA, b2A); LOADB(63, bA, b2A);
    COMPUTE(61, bB, b2B);
    COMPUTE(62, bC, b2C);
    COMPUTE(63, bA, b2A);
#undef LOADB
#undef COMPUTE

    // epilogue: combine the two u-streams via LDS (red aliases Ctb)
    __syncthreads();
    if (ust == 1) {
#pragma unroll
        for (int q = 0; q < 4; ++q) {
#pragma unroll
            for (int rr = 0; rr < 4; ++rr) {
                int reg = q * 4 + rr;
                int el = esub * 32 + q * 8 + half * 4 + rr;
                int e = e0 + el; int ec = e < E ? e : E - 1;
                float4 sv = *(const float4*)(sh + (size_t)ec * 4);
                red[(((esub * 4 + 0) * 16 + reg) << 6) + lane] = acc0[reg];
                red[(((esub * 4 + 1) * 16 + reg) << 6) + lane] = sv.y * accB[reg] + accC0[reg];
                red[(((esub * 4 + 2) * 16 + reg) << 6) + lane] = sv.z * accB[reg] + accC1[reg];
                red[(((esub * 4 + 3) * 16 + reg) << 6) + lane] = sv.w * accB[reg] + accC2[reg];
            }
        }
    }
    __syncthreads();
    if (ust == 0) {
#pragma unroll
        for (int q = 0; q < 4; ++q) {
#pragma unroll
            for (int rr = 0; rr < 4; ++rr) {
                int reg = q * 4 + rr;
                int el = esub * 32 + q * 8 + half * 4 + rr;
                int e = e0 + el;
                if (e >= E) continue;
                float4 sv = *(const float4*)(sh + (size_t)e * 4);
                float a0 = acc0[reg] + red[(((esub * 4 + 0) * 16 + reg) << 6) + lane];
                float o0 = sv.y * accB[reg] + accC0[reg] + red[(((esub * 4 + 1) * 16 + reg) << 6) + lane];
                float o1 = sv.z * accB[reg] + accC1[reg] + red[(((esub * 4 + 2) * 16 + reg) << 6) + lane];
                float o2 = sv.w * accB[reg] + accC2[reg] + red[(((esub * 4 + 3) * 16 + reg) << 6) + lane];
                float* tpe = tp + (size_t)e * 128;
                tpe[col] = a0;
                tpe[32 + col * 3 + 0] = o0;
                tpe[32 + col * 3 + 1] = o1;
                tpe[32 + col * 3 + 2] = o2;
            }
        }
    }
}

// ---- K_scan: exclusive prefix sum of deg -> rowptr (1 WG) ----
__global__ __launch_bounds__(1024) void k_scan(const int* __restrict__ deg,
                                               int* __restrict__ rowptr, int N) {
    __shared__ int part[1024];
    const int tid = threadIdx.x;
    const int chunk = (N + 1023) / 1024;
    const int base = tid * chunk;
    int s = 0;
    for (int i = 0; i < chunk; ++i) {
        int n = base + i;
        if (n < N) s += deg[n];
    }
    part[tid] = s;
    __syncthreads();
    for (int off = 1; off < 1024; off <<= 1) {
        int t = 0;
        if (tid >= off) t = part[tid - off];
        __syncthreads();
        if (tid >= off) part[tid] += t;
        __syncthreads();
    }
    int prefix = (tid == 0) ? 0 : part[tid - 1];
    for (int i = 0; i < chunk; ++i) {
        int n = base + i;
        if (n < N) { rowptr[n] = prefix; prefix += deg[n]; }
    }
    if (tid == 0) rowptr[N] = part[1023];
}

// ---- K4: per-node gather-mean + residual + BN stats ----
__global__ __launch_bounds__(256) void k4_gather(const float* __restrict__ tp,
                                                 const int* __restrict__ rowptr,
                                                 const int* __restrict__ elist,
                                                 const float* __restrict__ na,
                                                 float* __restrict__ pre,
                                                 float* __restrict__ stats, int N) {
    __shared__ float bns[96];
    const int tid = threadIdx.x;
    if (tid < 96) bns[tid] = 0.f;
    __syncthreads();
    const int o = tid & 127, hf = tid >> 7;
    for (int n = blockIdx.x * 2 + hf; n < N; n += gridDim.x * 2) {
        int r0 = rowptr[n], r1 = rowptr[n + 1];
        float s = 0.f;
        for (int j = r0; j < r1; ++j)
            s += tp[(size_t)elist[j] * 128 + o];
        int dg = r1 - r0;
        float cf = (float)(dg > 0 ? dg : 1);
        float v = s / cf + na[(size_t)n * 128 + o];
        pre[(size_t)n * 128 + o] = v;
        if (o < 32) {
            atomicAdd(&bns[o], v);
            atomicAdd(&bns[32 + o], v * v);
        } else {
            atomicAdd(&bns[64 + (o - 32) / 3], v * v);
        }
    }
    __syncthreads();
    if (tid < 96) atomicAdd(&stats[tid], bns[tid]);
}

// ---- K5: apply batch norm ----
__global__ __launch_bounds__(256) void k5_bn(const float* __restrict__ pre,
                                             const float* __restrict__ stats,
                                             const float* __restrict__ bnw,
                                             const float* __restrict__ bnb,
                                             float* __restrict__ out, int N) {
    size_t idx = (size_t)blockIdx.x * 256 + threadIdx.x;
    if (idx >= (size_t)N * 128) return;
    int o = (int)(idx & 127);
    float v = pre[idx];
    float invN = 1.f / (float)N;
    if (o < 32) {
        float m   = stats[o] * invN;
        float var = stats[32 + o] * invN - m * m;
        out[idx] = (v - m) * rsqrtf(var + EPSV) * bnw[o] + bnb[o];
    } else {
        int j = (o - 32) / 3;
        float vn = rsqrtf(stats[64 + j] * invN * (1.f / 3.f) + EPSV);
        out[idx] = v * vn * bnw[32 + j];
    }
}

extern "C" void kernel_launch(void* const* d_in, const int* in_sizes, int n_in,
                              void* d_out, int out_size, void* d_ws, size_t ws_size,
                              hipStream_t stream) {
    const float* node_attr  = (const float*)d_in[0];
    const int*   edge_index = (const int*)d_in[1];
    const float* edge_attr  = (const float*)d_in[2];
    const float* edge_sh    = (const float*)d_in[3];
    const float* W1  = (const float*)d_in[4];
    const float* b1  = (const float*)d_in[5];
    const float* W2  = (const float*)d_in[6];
    const float* b2  = (const float*)d_in[7];
    const float* bnw = (const float*)d_in[8];
    const float* bnb = (const float*)d_in[9];

    const int N = in_sizes[0] / 128;
    const int E = in_sizes[1] / 2;
    const int ngroups = ((E + 127) / 128) * 4;

    float* tp     = (float*)d_ws;                 // E*128
    float* pre    = tp + (size_t)E * 128;         // N*128
    float* stats  = pre + (size_t)N * 128;        // 96
    int*   deg    = (int*)(stats + 96);           // N
    int*   cursor = deg + N;                      // N
    int*   rowptr = cursor + N;                   // N+1
    int*   elist  = rowptr + N + 1;               // E
    char* pbase = (char*)(elist + E);
    pbase += (16 - ((size_t)pbase & 15)) & 15;    // align 16
    unsigned short* hsw = (unsigned short*)pbase;          // ngroups*4096 bf16
    unsigned short* W2T = hsw + (size_t)ngroups * 4096;    // 524288
    unsigned short* W1T = W2T + (size_t)524288;            // 16384

    const int zn = 96 + 2 * N;                    // stats+deg+cursor (contiguous)
    const int zblocks = (zn + 255) / 256;

    k0_tile<<<132 + zblocks, 256, 0, stream>>>(W2, W1, W2T, W1T, (int*)stats, zn);
    k1_fc<<<(E + 127) / 128, 256, 0, stream>>>(edge_attr, W1T, b1, edge_index, hsw, deg, E);
    k_scan<<<1, 1024, 0, stream>>>(deg, rowptr, N);
    k2_mfma<<<(E + 63) / 64, 256, 0, stream>>>(hsw, W2T, b2, node_attr, edge_index,
                                               edge_sh, rowptr, cursor, elist, tp, E);
    k4_gather<<<1024, 256, 0, stream>>>(tp, rowptr, elist, node_attr, pre, stats, N);
    size_t ntot = (size_t)N * 128;
    k5_bn<<<(int)((ntot + 255) / 256), 256, 0, stream>>>(pre, stats, bnw, bnb,
                                                         (float*)d_out, N);
}